// Round 14
// baseline (6775.900 us; speedup 1.0000x reference)
//
#include <hip/hip_runtime.h>
#include <stdint.h>

// ============================================================================
// RandomMaskSubgraphs on gfx950. Round 14 (perf; passing since R10).
// R13: sums 3.44ms = 8.25cyc/dep-add (2x v_add dep latency). Hypothesis:
// chain wave loses issue arbitration to 3 co-SIMD staging waves. Fix: T5
// s_setprio(3) on chain wave + ping-pong register unroll (no v_mov rotation).
// Tail: BLK scan (59083 entries, 1 block, 231 serial iters ~300-400us) ->
// hierarchical 3-launch scan; same for SBLK scans. FP order bit-identical.
// ============================================================================
#define PARTITIONABLE 1
#define SUM_LANES 8

#define E_EDGES   8000000
#define NVERT     44000
#define N_EXT     2000000
#define N_NEW     6400000
#define ROWS_LEN  4044000
#define SROWS_LEN 844000
#define DEC_LEN   16888000
#define BMP_WORDS 60500000
#define NSCB      59083
#define NBLK_E    1954
#define NSCB_B    231    // ceil(NSCB/256)
#define NBLK_B    8      // ceil(NBLK_E/256)

#define SPAN_EXT  4044000u
#define SPAN_NEW  6000000u

// ---- output f32-element offsets (natural return order) ----
#define O0 0LL
#define O1 8088000LL
#define O2 12132000LL
#define O3 45908000LL
#define O4 62796000LL
#define O5 64484000LL
#define O6 65328000LL
#define O7 67016000LL
#define OUT_TOTAL 67860000

#define SC_SKEEP  0
#define SC_SSUB   1
#define SC_PREFIX 2
#define SC_KPRIME 3
#define SC_T      4
#define SC_M      5
#define SC_EQC    6
#define SC_EQN    7
#define SC_MUNIQ  8
#define SC_HIST   16
#define SC_PART   512   // scan partials (up to 231 words)

struct TF2 { uint32_t a, b; };

__host__ __device__ __forceinline__ TF2 tf2x32(uint32_t k0, uint32_t k1,
                                               uint32_t c0, uint32_t c1) {
  uint32_t ks2 = k0 ^ k1 ^ 0x1BD11BDAu;
  uint32_t x0 = c0 + k0, x1 = c1 + k1;
#define TFR(r) { x0 += x1; x1 = (x1 << (r)) | (x1 >> (32 - (r))); x1 ^= x0; }
  TFR(13) TFR(15) TFR(26) TFR(6)   x0 += k1;  x1 += ks2 + 1u;
  TFR(17) TFR(29) TFR(16) TFR(24)  x0 += ks2; x1 += k0 + 2u;
  TFR(13) TFR(15) TFR(26) TFR(6)   x0 += k0;  x1 += k1 + 3u;
  TFR(17) TFR(29) TFR(16) TFR(24)  x0 += k1;  x1 += ks2 + 4u;
  TFR(13) TFR(15) TFR(26) TFR(6)   x0 += ks2; x1 += k0 + 5u;
#undef TFR
  TF2 r; r.a = x0; r.b = x1; return r;
}

__device__ __forceinline__ uint32_t rbits(uint2 k, uint32_t i, uint32_t half) {
#if PARTITIONABLE
  TF2 r = tf2x32(k.x, k.y, 0u, i);
  return r.a ^ r.b;
#else
  if (i < half) return tf2x32(k.x, k.y, i, half + i).a;
  return tf2x32(k.x, k.y, i - half, i).b;
#endif
}

// jax randint, faithful uint32 device semantics (mult wraps to 0 for our spans)
__device__ __forceinline__ uint32_t jrandint(uint2 k1, uint2 k2, uint32_t i,
                                             uint32_t half, uint32_t span) {
  uint32_t m1 = 65536u % span;
  uint32_t mult = (m1 * m1) % span;
  uint32_t hb = (mult != 0u) ? rbits(k1, i, half) : 0u;
  uint32_t lb = rbits(k2, i, half);
  uint32_t off = (hb % span) * mult + (lb % span);
  return off % span;
}

__device__ __forceinline__ float unif_from_bits(uint32_t bits) {
#pragma clang fp contract(off)
  float f = __uint_as_float((bits >> 9) | 0x3f800000u) - 1.0f;
  float u = f + 1e-12f;
  return fmaxf(1e-12f, u);
}

// XLA:CPU GenerateVF32Log == Eigen 3.3 plog port, plain mul/add (no fma).
__device__ __forceinline__ float xla_logf(float x) {
#pragma clang fp contract(off)
  uint32_t bx = __float_as_uint(x);
  int emm0 = (int)(bx >> 23) - 127;
  float m = __uint_as_float((bx & 0x007fffffu) | 0x3f000000u);
  float e = 1.0f + (float)emm0;
  bool lt = (m < 0.707106781186547524f);
  float tmp1 = lt ? m : 0.0f;
  float t = m - 1.0f;
  e = e - (lt ? 1.0f : 0.0f);
  t = t + tmp1;
  float x2 = t * t;
  float x3 = x2 * t;
  float y, y1, y2;
  y  = t * 7.0376836292e-2f  + -1.1514610310e-1f;
  y1 = t * -1.2420140846e-1f +  1.4249322787e-1f;
  y2 = t * 2.0000714765e-1f  + -2.4999993993e-1f;
  y  = y  * t +  1.1676998740e-1f;
  y1 = y1 * t + -1.6668057665e-1f;
  y2 = y2 * t +  3.3333331174e-1f;
  y = y * x3 + y1;
  y = y * x3 + y2;
  y = y * x3;
  y1 = -2.12194440e-4f * e;
  float tmp2 = 0.5f * x2;
  y = y + y1;
  t = t - tmp2;
  y2 = 0.693359375f * e;
  t = t + y;
  t = t + y2;
  return t;
}

__device__ __forceinline__ float xla_expf(float x) {
#pragma clang fp contract(off)
  x = fminf(x, 88.3762626647950f);
  x = fmaxf(x, -88.3762626647949f);
  float fx = x * 1.44269504088896341f + 0.5f;
  float flr = floorf(fx);
  float t1 = flr * 0.693359375f;
  float t2 = flr * -2.12194440e-4f;
  x = x - t1;
  x = x - t2;
  float z = x * x;
  float y = 1.9875691500e-4f;
  y = y * x + 1.3981999507e-3f;
  y = y * x + 8.3334519073e-3f;
  y = y * x + 4.1665795894e-2f;
  y = y * x + 1.6666665459e-1f;
  y = y * x + 5.0000001201e-1f;
  y = y * z;
  y = y + x;
  y = y + 1.0f;
  int n = (int)flr;
  float p2n = __uint_as_float((uint32_t)(n + 127) << 23);
  return y * p2n;
}

__device__ __forceinline__ uint32_t score_key(float w, float S, float u) {
#pragma clang fp contract(off)
  float p = w / S;
  float lu = xla_logf(u);
  float g = xla_logf(-lu);
  float s = xla_logf(p) - g;
  uint32_t b = __float_as_uint(s);
  return (b & 0x80000000u) ? ~b : (b | 0x80000000u);
}

// ---------------------------------------------------------------------------
__global__ void zero_kernel(uint32_t* p, long long n) {
  long long i = (long long)blockIdx.x * blockDim.x + threadIdx.x;
  long long stride = (long long)gridDim.x * blockDim.x;
  for (; i < n; i += stride) p[i] = 0u;
}

__global__ void sentinel_kernel(float* outb, float code) {
  if (blockIdx.x == 0 && threadIdx.x == 0) outb[0] = code;
}

__global__ void w_kernel(const float* att, float* warr) {
#pragma clang fp contract(off)
  int i = blockIdx.x * 256 + threadIdx.x;
  if (i >= E_EDGES) return;
  float c = fminf(att[i], 3.0f);
  float x = c + 1e-8f;
  warr[i] = 1.0f / xla_expf(x);
}

// Exact-order sums, transposed-LDS pipeline + setprio'd chain wave.
#define SUMS_CH  16000
#define SUMS_V4  4000
#define PSTRIPE  2004
#define SUMS_B4  10
#define SUMS_NB  50
#define SUMS_NCH 500
__global__ __launch_bounds__(1024) void sums_kernel(const float* warr, const float* att, float* scf) {
#pragma clang fp contract(off)
  __shared__ __align__(16) float buf0[8 * PSTRIPE];
  __shared__ __align__(16) float buf1[8 * PSTRIPE];
  __shared__ float lanes[SUM_LANES];
  int t = threadIdx.x;
  int which = blockIdx.x;
  const float4* src4 = (const float4*)(which == 0 ? warr : att);

  if (t < 64) __builtin_amdgcn_s_setprio(3);   // chain wave wins issue arbitration

  if (t >= 64) {
    for (int q = t - 64; q < SUMS_V4; q += 960) {
      float4 v = src4[q];
      if (which == 1) {
        v.x = fminf(v.x, 3.0f) + 0.001f;
        v.y = fminf(v.y, 3.0f) + 0.001f;
        v.z = fminf(v.z, 3.0f) + 0.001f;
        v.w = fminf(v.w, 3.0f) + 0.001f;
      }
      int k = q >> 1;
      int s0 = (q & 1) * 4;
      buf0[(s0 + 0) * PSTRIPE + k] = v.x;
      buf0[(s0 + 1) * PSTRIPE + k] = v.y;
      buf0[(s0 + 2) * PSTRIPE + k] = v.z;
      buf0[(s0 + 3) * PSTRIPE + k] = v.w;
    }
  }
  __syncthreads();

  float acc = 0.0f;
  for (int c = 0; c < SUMS_NCH; ++c) {
    float* curb = (c & 1) ? buf1 : buf0;
    float* nxtb = (c & 1) ? buf0 : buf1;
    if (t >= 64) {
      if (c + 1 < SUMS_NCH) {
        const float4* base = src4 + (long long)(c + 1) * SUMS_V4;
        for (int q = t - 64; q < SUMS_V4; q += 960) {
          float4 v = base[q];
          if (which == 1) {
            v.x = fminf(v.x, 3.0f) + 0.001f;
            v.y = fminf(v.y, 3.0f) + 0.001f;
            v.z = fminf(v.z, 3.0f) + 0.001f;
            v.w = fminf(v.w, 3.0f) + 0.001f;
          }
          int k = q >> 1;
          int s0 = (q & 1) * 4;
          nxtb[(s0 + 0) * PSTRIPE + k] = v.x;
          nxtb[(s0 + 1) * PSTRIPE + k] = v.y;
          nxtb[(s0 + 2) * PSTRIPE + k] = v.z;
          nxtb[(s0 + 3) * PSTRIPE + k] = v.w;
        }
      }
    } else if (t < SUM_LANES) {
      // ping-pong prefetch: no register rotation moves
      const float4* stripe4 = (const float4*)(curb + t * PSTRIPE);
      float4 A[SUMS_B4], B[SUMS_B4];
#pragma unroll
      for (int u = 0; u < SUMS_B4; ++u) A[u] = stripe4[u];
      for (int b = 0; b < SUMS_NB; b += 2) {
#pragma unroll
        for (int u = 0; u < SUMS_B4; ++u) B[u] = stripe4[(b + 1) * SUMS_B4 + u];
#pragma unroll
        for (int u = 0; u < SUMS_B4; ++u) {
          acc += A[u].x; acc += A[u].y; acc += A[u].z; acc += A[u].w;
        }
        if (b + 2 < SUMS_NB) {
#pragma unroll
          for (int u = 0; u < SUMS_B4; ++u) A[u] = stripe4[(b + 2) * SUMS_B4 + u];
        }
#pragma unroll
        for (int u = 0; u < SUMS_B4; ++u) {
          acc += B[u].x; acc += B[u].y; acc += B[u].z; acc += B[u].w;
        }
      }
    }
    __syncthreads();
  }

  if (t < SUM_LANES) lanes[t] = acc;
  __syncthreads();
  if (t == 0) {
    float v[SUM_LANES];
    for (int q = 0; q < SUM_LANES; ++q) v[q] = lanes[q];
    int w = SUM_LANES;
    while (w > 1) { int h = w >> 1; for (int q = 0; q < h; ++q) v[q] = v[q] + v[q + h]; w = h; }
    scf[which] = v[0];
  }
}

__global__ void keys_kernel(const float* warr, const float* att, const float* scf,
                            uint32_t* keys, uint2 kk, int mode) {
  int i = blockIdx.x * 256 + threadIdx.x;
  if (i >= E_EDGES) return;
  float S = (mode == 1) ? scf[SC_SSUB] : scf[SC_SKEEP];
  float w;
  if (mode == 1) { float a = att[i]; w = fminf(a, 3.0f) + 0.001f; }
  else w = warr[i];
  uint32_t b = rbits(kk, (uint32_t)i, 4000000u);
  keys[i] = score_key(w, S, unif_from_bits(b));
}

__global__ void sel_reset_kernel(uint32_t* sc, uint32_t k) {
  int t = threadIdx.x;
  sc[SC_HIST + t] = 0u;
  if (t == 0) { sc[SC_PREFIX] = 0u; sc[SC_KPRIME] = k; sc[SC_EQC] = 0u; sc[SC_EQN] = 0u; }
}

__global__ void sel_hist_kernel(const uint32_t* keys, uint32_t* sc, int round) {
  __shared__ uint32_t h[256];
  int t = threadIdx.x;
  h[t] = 0u;
  __syncthreads();
  uint32_t pref = sc[SC_PREFIX];
  int shift = 24 - 8 * round;
  uint32_t maskHi = (round == 0) ? 0u : (0xFFFFFFFFu << (shift + 8));
  int i = blockIdx.x * 4096 + t;
#pragma unroll
  for (int it = 0; it < 16; ++it, i += 256) {
    if (i < E_EDGES) {
      uint32_t key = keys[i];
      if (((key ^ pref) & maskHi) == 0u) atomicAdd(&h[(key >> shift) & 0xffu], 1u);
    }
  }
  __syncthreads();
  if (h[t]) atomicAdd(&sc[SC_HIST + t], h[t]);
}

__global__ void sel_pick_kernel(uint32_t* sc, int round) {
  if (blockIdx.x != 0 || threadIdx.x != 0) return;
  uint32_t kprime = sc[SC_KPRIME];
  int shift = 24 - 8 * round;
  uint32_t cum = 0; uint32_t bsel = 0;
  for (int b = 255; b >= 0; --b) {
    uint32_t c = sc[SC_HIST + b];
    if (cum + c >= kprime) { bsel = (uint32_t)b; break; }
    cum += c;
  }
  sc[SC_PREFIX] |= bsel << shift;
  sc[SC_KPRIME] = kprime - cum;
  for (int b = 0; b < 256; ++b) sc[SC_HIST + b] = 0u;
  if (round == 3) { sc[SC_T] = sc[SC_PREFIX]; sc[SC_M] = sc[SC_KPRIME]; }
}

__global__ void eq_collect_kernel(const uint32_t* keys, uint32_t* sc, uint32_t* eql) {
  int i = blockIdx.x * 256 + threadIdx.x;
  if (i >= E_EDGES) return;
  if (keys[i] == sc[SC_T]) {
    uint32_t p = atomicAdd(&sc[SC_EQC], 1u);
    if (p < 4096u) eql[p] = (uint32_t)i;
  }
}

__global__ void eq_sort_kernel(uint32_t* sc, uint32_t* eql) {
  if (blockIdx.x != 0 || threadIdx.x != 0) return;
  uint32_t n = sc[SC_EQC]; if (n > 4096u) n = 4096u;
  sc[SC_EQN] = n;
  for (uint32_t a = 1; a < n; ++a) {
    uint32_t v = eql[a]; uint32_t b = a;
    while (b > 0 && eql[b - 1] > v) { eql[b] = eql[b - 1]; --b; }
    eql[b] = v;
  }
}

__device__ __forceinline__ int keep_flag(uint32_t key, uint32_t T, uint32_t m,
                                         const uint32_t* eql, uint32_t eqn, uint32_t i) {
  if (key > T) return 1;
  if (key != T) return 0;
  uint32_t lo = 0, hi = eqn;
  while (lo < hi) { uint32_t mid = (lo + hi) >> 1; if (eql[mid] < i) lo = mid + 1; else hi = mid; }
  return (lo < m) ? 1 : 0;
}

__global__ void cnt_flags_kernel(const uint32_t* keys, const uint32_t* sc,
                                 const uint32_t* eql, uint32_t* sblk) {
  __shared__ uint32_t s[256];
  int t = threadIdx.x;
  uint32_t T = sc[SC_T], m = sc[SC_M], eqn = sc[SC_EQN];
  int base = blockIdx.x * 4096 + t * 16;
  uint32_t cnt = 0;
#pragma unroll
  for (int j = 0; j < 16; ++j) {
    int i = base + j;
    if (i < E_EDGES) cnt += keep_flag(keys[i], T, m, eql, eqn, (uint32_t)i);
  }
  s[t] = cnt;
  __syncthreads();
  for (int off = 128; off > 0; off >>= 1) { if (t < off) s[t] += s[t + off]; __syncthreads(); }
  if (t == 0) sblk[blockIdx.x] = s[0];
}

// single-block scan (used for <=256-entry partial arrays)
__global__ void scan_small_kernel(uint32_t* a, int n, uint32_t* totalOut) {
  __shared__ uint32_t s[256];
  int t = threadIdx.x;
  uint32_t carry = 0;
  for (int base = 0; base < n; base += 256) {
    int idx = base + t;
    uint32_t v = (idx < n) ? a[idx] : 0u;
    s[t] = v;
    __syncthreads();
    for (int off = 1; off < 256; off <<= 1) {
      uint32_t x = 0; if (t >= off) x = s[t - off];
      __syncthreads();
      if (t >= off) s[t] += x;
      __syncthreads();
    }
    uint32_t incl = s[t];
    uint32_t tot = s[255];
    if (idx < n) a[idx] = incl - v + carry;
    carry += tot;
    __syncthreads();
  }
  if (t == 0 && totalOut) *totalOut = carry;
}

// hierarchical scan: per-block exclusive + block totals
__global__ void hscan1_kernel(uint32_t* a, int n, uint32_t* part) {
  __shared__ uint32_t s[256];
  int t = threadIdx.x;
  int idx = blockIdx.x * 256 + t;
  uint32_t v = (idx < n) ? a[idx] : 0u;
  s[t] = v;
  __syncthreads();
  for (int off = 1; off < 256; off <<= 1) {
    uint32_t x = 0; if (t >= off) x = s[t - off];
    __syncthreads();
    if (t >= off) s[t] += x;
    __syncthreads();
  }
  if (idx < n) a[idx] = s[t] - v;
  if (t == 255) part[blockIdx.x] = s[255];
}

__global__ void hscan3_kernel(uint32_t* a, int n, const uint32_t* part) {
  int idx = blockIdx.x * 256 + threadIdx.x;
  if (idx < n) a[idx] += part[blockIdx.x];
}

__global__ void scatter_kernel(const uint32_t* keys, const uint32_t* sc, const uint32_t* eql,
                               const uint32_t* sblk, int* kidx, int* didx, int writeDrop) {
  __shared__ uint32_t s[256];
  int t = threadIdx.x;
  uint32_t T = sc[SC_T], m = sc[SC_M], eqn = sc[SC_EQN];
  int base = blockIdx.x * 4096 + t * 16;
  uint32_t fbits = 0, cnt = 0;
#pragma unroll
  for (int j = 0; j < 16; ++j) {
    int i = base + j; int f = 0;
    if (i < E_EDGES) f = keep_flag(keys[i], T, m, eql, eqn, (uint32_t)i);
    fbits |= ((uint32_t)f) << j; cnt += (uint32_t)f;
  }
  s[t] = cnt;
  __syncthreads();
  for (int off = 1; off < 256; off <<= 1) {
    uint32_t x = 0; if (t >= off) x = s[t - off];
    __syncthreads();
    if (t >= off) s[t] += x;
    __syncthreads();
  }
  uint32_t run = sblk[blockIdx.x] + (s[t] - cnt);
  for (int j = 0; j < 16; ++j) {
    int i = base + j;
    if (i >= E_EDGES) break;
    if ((fbits >> j) & 1u) {
      if (run < 4000000u) kidx[run] = i;
      run++;
    } else if (writeDrop) {
      uint32_t d = (uint32_t)i - run;
      if (d < 4000000u) didx[d] = i;
    }
  }
}

__global__ void build_rows_kernel(const int* kidx, const int* ar, const int* ac,
                                  int* rows, int* cols, int total) {
  int i = blockIdx.x * 256 + threadIdx.x;
  if (i >= total) return;
  if (i < NVERT) { rows[i] = i; cols[i] = i; }
  else {
    int j = kidx[i - NVERT];
    j = (j < 0) ? 0 : (j >= E_EDGES ? E_EDGES - 1 : j);
    rows[i] = ar[j]; cols[i] = ac[j];
  }
}

__global__ void deg_count_kernel(const int* rows, int* deg, int len) {
  int i = blockIdx.x * 256 + threadIdx.x;
  if (i >= len) return;
  int r = rows[i];
  r = (r < 0) ? 0 : (r >= NVERT ? NVERT - 1 : r);
  atomicAdd(&deg[r], 1);
}

__global__ void deg_inv_kernel(const int* deg, float* dinv) {
  int i = blockIdx.x * 256 + threadIdx.x;
  if (i >= NVERT) return;
  int d = deg[i];
  dinv[i] = (d > 0) ? (float)(1.0 / sqrt((double)d)) : 0.0f;
}

__global__ void graph_out_kernel(const int* rows, const int* cols, const float* dinv,
                                 float* outb, long long idxOff, long long valOff, int len) {
#pragma clang fp contract(off)
  int i = blockIdx.x * 256 + threadIdx.x;
  if (i >= len) return;
  int r = rows[i], c = cols[i];
  r = (r < 0) ? 0 : (r >= NVERT ? NVERT - 1 : r);
  c = (c < 0) ? 0 : (c >= NVERT ? NVERT - 1 : c);
  outb[idxOff + i] = (float)r;
  outb[idxOff + len + i] = (float)c;
  outb[valOff + i] = dinv[r] * dinv[c];
}

__global__ void newrc_kernel(const int* rows, const int* cols, const int* didx,
                             const int* ar, const int* ac, int* newr, int* newc,
                             uint2 knr1, uint2 knr2, uint2 knc1, uint2 knc2,
                             uint2 ker1, uint2 ker2, uint2 kec1, uint2 kec2) {
  int i = blockIdx.x * 256 + threadIdx.x;
  if (i >= N_NEW) return;
  uint32_t nr = jrandint(knr1, knr2, (uint32_t)i, 3200000u, SPAN_NEW);
  int v;
  if (nr < (uint32_t)N_EXT) {
    uint32_t e = jrandint(ker1, ker2, nr, 1000000u, SPAN_EXT);
    v = rows[e];
  } else {
    int d = didx[nr - (uint32_t)N_EXT];
    d = (d < 0) ? 0 : (d >= E_EDGES ? E_EDGES - 1 : d);
    v = ar[d];
  }
  newr[i] = v;
  uint32_t nc = jrandint(knc1, knc2, (uint32_t)i, 3200000u, SPAN_NEW);
  if (nc < (uint32_t)N_EXT) {
    uint32_t e = jrandint(kec1, kec2, nc, 1000000u, SPAN_EXT);
    v = cols[e];
  } else {
    int d = didx[nc - (uint32_t)N_EXT];
    d = (d < 0) ? 0 : (d >= E_EDGES ? E_EDGES - 1 : d);
    v = ac[d];
  }
  newc[i] = v;
}

__global__ void bmp_mark_kernel(const int* newr, const int* newc,
                                const int* rows, const int* cols, uint32_t* bmp) {
  int i = blockIdx.x * 256 + threadIdx.x;
  if (i >= DEC_LEN) return;
  int r, c;
  if (i < N_NEW) { r = newr[i]; c = newc[i]; }
  else if (i < 2 * N_NEW) { r = newc[i - N_NEW]; c = newr[i - N_NEW]; }
  else if (i < 2 * N_NEW + NVERT) { r = i - 2 * N_NEW; c = r; }
  else { int q = i - (2 * N_NEW + NVERT); r = rows[q]; c = cols[q]; }
  r = (r < 0) ? 0 : (r >= NVERT ? NVERT - 1 : r);
  c = (c < 0) ? 0 : (c >= NVERT ? NVERT - 1 : c);
  uint32_t h = (uint32_t)r * 44000u + (uint32_t)c;
  atomicOr(&bmp[h >> 5], 1u << (h & 31u));
}

__global__ void bmp_cnt_kernel(const uint32_t* bmp, uint32_t* blk) {
  __shared__ uint32_t s[256];
  int t = threadIdx.x;
  long long wbase = (long long)blockIdx.x * 1024 + (long long)t * 4;
  uint32_t c = 0;
#pragma unroll
  for (int j = 0; j < 4; ++j) {
    long long w = wbase + j;
    if (w < (long long)BMP_WORDS) c += __popc(bmp[w]);
  }
  s[t] = c;
  __syncthreads();
  for (int off = 128; off > 0; off >>= 1) { if (t < off) s[t] += s[t + off]; __syncthreads(); }
  if (t == 0) blk[blockIdx.x] = s[0];
}

__global__ void dec_out_kernel(const uint32_t* bmp, const uint32_t* blk, float* outb) {
  __shared__ uint32_t s[256];
  int t = threadIdx.x;
  long long wbase = (long long)blockIdx.x * 1024 + (long long)t * 4;
  uint32_t cn[4]; uint32_t tot = 0;
#pragma unroll
  for (int j = 0; j < 4; ++j) {
    long long w = wbase + j;
    cn[j] = (w < (long long)BMP_WORDS) ? (uint32_t)__popc(bmp[w]) : 0u;
    tot += cn[j];
  }
  s[t] = tot;
  __syncthreads();
  for (int off = 1; off < 256; off <<= 1) {
    uint32_t x = 0; if (t >= off) x = s[t - off];
    __syncthreads();
    if (t >= off) s[t] += x;
    __syncthreads();
  }
  uint32_t pos = blk[blockIdx.x] + (s[t] - tot);
  for (int j = 0; j < 4; ++j) {
    long long w = wbase + j;
    if (w >= (long long)BMP_WORDS) break;
    uint32_t word = bmp[w];
    while (word) {
      int b = __ffs(word) - 1;
      word &= word - 1u;
      uint32_t v = (uint32_t)w * 32u + (uint32_t)b;
      uint32_t ur = v / 44000u;
      uint32_t uc = v - ur * 44000u;
      if (pos < (uint32_t)DEC_LEN) {
        outb[O2 + pos] = (float)ur;
        outb[O2 + DEC_LEN + pos] = (float)uc;
        outb[O3 + pos] = 1.0f;
      }
      pos++;
    }
  }
}

__global__ void dec_pad_kernel(float* outb, const uint32_t* sc) {
  int p = blockIdx.x * 256 + threadIdx.x;
  if (p >= DEC_LEN) return;
  if ((uint32_t)p >= sc[SC_MUNIQ]) {
    outb[O2 + p] = 0.0f; outb[O2 + DEC_LEN + p] = 0.0f; outb[O3 + p] = 0.0f;
  }
}

// ---------------------------------------------------------------------------
static void jsplit2(uint2 k, uint2& k1, uint2& k2) {
#if PARTITIONABLE
  TF2 a = tf2x32(k.x, k.y, 0u, 0u), b = tf2x32(k.x, k.y, 0u, 1u);
  k1.x = a.a; k1.y = a.b; k2.x = b.a; k2.y = b.b;
#else
  TF2 a = tf2x32(k.x, k.y, 0u, 2u), b = tf2x32(k.x, k.y, 1u, 3u);
  k1.x = a.a; k1.y = b.a; k2.x = a.b; k2.y = b.b;
#endif
}

extern "C" void kernel_launch(void* const* d_in, const int* in_sizes, int n_in,
                              void* d_out, int out_size, void* d_ws, size_t ws_size,
                              hipStream_t stream) {
  float* outb = (float*)d_out;

  if (out_size != OUT_TOTAL) {
    sentinel_kernel<<<1, 64, 0, stream>>>(outb, 16777216.0f);
    return;
  }
  if (n_in < 4 || in_sizes[0] != E_EDGES || in_sizes[3] != E_EDGES) {
    sentinel_kernel<<<1, 64, 0, stream>>>(outb, 20971520.0f);
    return;
  }
  if (ws_size < 429300000ULL) {
    sentinel_kernel<<<1, 64, 0, stream>>>(outb, 25165824.0f);
    return;
  }

  const int* adj_rows = (const int*)d_in[0];
  const int* adj_cols = (const int*)d_in[1];
  const float* att = (const float*)d_in[3];
  char* ws = (char*)d_ws;

  uint32_t* KEYS  = (uint32_t*)(ws + 0LL);
  float*    WARR  = (float*)(ws + 32000000LL);
  int*      KIDX  = (int*)(ws + 64000000LL);
  int*      DIDX  = (int*)(ws + 80000000LL);
  int*      ROWS  = (int*)(ws + 96000000LL);
  int*      COLS  = (int*)(ws + 112176000LL);
  int*      NEWR  = (int*)(ws + 128352000LL);
  int*      NEWC  = (int*)(ws + 153952000LL);
  uint32_t* BMP   = (uint32_t*)(ws + 179552000LL);
  uint32_t* BLK   = (uint32_t*)(ws + 421552000LL);
  int*      DEG   = (int*)(ws + 421788544LL);
  float*    DINV  = (float*)(ws + 421964544LL);
  uint32_t* SBLK  = (uint32_t*)(ws + 422140544LL);
  uint32_t* SC    = (uint32_t*)(ws + 422148736LL);
  uint32_t* EQL   = (uint32_t*)(ws + 422152832LL);
  int*      CMPR  = (int*)(ws + 422169216LL);
  int*      CMPC  = (int*)(ws + 425545216LL);
  float*    DINVS = (float*)(ws + 428921216LL);
  float*    DINVC = (float*)(ws + 429097216LL);
  uint32_t* PART  = SC + SC_PART;

  TF2 K[7];
#if PARTITIONABLE
  for (int i = 0; i < 7; ++i) K[i] = tf2x32(0u, 42u, 0u, (uint32_t)i);
#else
  {
    TF2 T_[7];
    for (int i = 0; i < 7; ++i) T_[i] = tf2x32(0u, 42u, (uint32_t)i, (uint32_t)(7 + i));
    K[0].a = T_[0].a; K[0].b = T_[1].a;
    K[1].a = T_[2].a; K[1].b = T_[3].a;
    K[2].a = T_[4].a; K[2].b = T_[5].a;
    K[3].a = T_[6].a; K[3].b = T_[0].b;
    K[4].a = T_[1].b; K[4].b = T_[2].b;
    K[5].a = T_[3].b; K[5].b = T_[4].b;
    K[6].a = T_[5].b; K[6].b = T_[6].b;
  }
#endif
  uint2 kkeep, ker, kec, knr, knc, ksub, kcmp;
  kkeep.x = K[0].a; kkeep.y = K[0].b;
  ker.x = K[1].a; ker.y = K[1].b;
  kec.x = K[2].a; kec.y = K[2].b;
  knr.x = K[3].a; knr.y = K[3].b;
  knc.x = K[4].a; knc.y = K[4].b;
  ksub.x = K[5].a; ksub.y = K[5].b;
  kcmp.x = K[6].a; kcmp.y = K[6].b;
  uint2 ker1, ker2, kec1, kec2, knr1, knr2, knc1, knc2;
  jsplit2(ker, ker1, ker2); jsplit2(kec, kec1, kec2);
  jsplit2(knr, knr1, knr2); jsplit2(knc, knc1, knc2);

  // === Phase A: init ===
  zero_kernel<<<4096, 256, 0, stream>>>(BMP, (long long)BMP_WORDS);
  zero_kernel<<<1, 256, 0, stream>>>(SC, 1024LL);
  zero_kernel<<<2048, 256, 0, stream>>>((uint32_t*)KIDX, 8000000LL);
  w_kernel<<<31250, 256, 0, stream>>>(att, WARR);
  sums_kernel<<<2, 1024, 0, stream>>>(WARR, att, (float*)SC);

  auto run_select = [&](uint32_t kcount) {
    sel_reset_kernel<<<1, 256, 0, stream>>>(SC, kcount);
    for (int r = 0; r < 4; ++r) {
      sel_hist_kernel<<<NBLK_E, 256, 0, stream>>>(KEYS, SC, r);
      sel_pick_kernel<<<1, 64, 0, stream>>>(SC, r);
    }
    eq_collect_kernel<<<31250, 256, 0, stream>>>(KEYS, SC, EQL);
    eq_sort_kernel<<<1, 64, 0, stream>>>(SC, EQL);
    cnt_flags_kernel<<<NBLK_E, 256, 0, stream>>>(KEYS, SC, EQL, SBLK);
    hscan1_kernel<<<NBLK_B, 256, 0, stream>>>(SBLK, NBLK_E, PART);
    scan_small_kernel<<<1, 256, 0, stream>>>(PART, NBLK_B, (uint32_t*)nullptr);
    hscan3_kernel<<<NBLK_B, 256, 0, stream>>>(SBLK, NBLK_E, PART);
  };

  // === Phase B: encoder keep selection (k=4M) -> ROWS/COLS/DINV ===
  keys_kernel<<<31250, 256, 0, stream>>>(WARR, att, (const float*)SC, KEYS, kkeep, 0);
  run_select(4000000u);
  scatter_kernel<<<NBLK_E, 256, 0, stream>>>(KEYS, SC, EQL, SBLK, KIDX, DIDX, 1);
  build_rows_kernel<<<15797, 256, 0, stream>>>(KIDX, adj_rows, adj_cols, ROWS, COLS, ROWS_LEN);
  zero_kernel<<<172, 256, 0, stream>>>((uint32_t*)DEG, (long long)NVERT);
  deg_count_kernel<<<15797, 256, 0, stream>>>(ROWS, DEG, ROWS_LEN);
  deg_inv_kernel<<<172, 256, 0, stream>>>(DEG, DINV);

  // === Phase C: decoder rewire + bitmap unique -> BMP/BLK/MUNIQ ===
  newrc_kernel<<<25000, 256, 0, stream>>>(ROWS, COLS, DIDX, adj_rows, adj_cols, NEWR, NEWC,
                                          knr1, knr2, knc1, knc2, ker1, ker2, kec1, kec2);
  bmp_mark_kernel<<<65969, 256, 0, stream>>>(NEWR, NEWC, ROWS, COLS, BMP);
  bmp_cnt_kernel<<<NSCB, 256, 0, stream>>>(BMP, BLK);
  hscan1_kernel<<<NSCB_B, 256, 0, stream>>>(BLK, NSCB, PART);
  scan_small_kernel<<<1, 256, 0, stream>>>(PART, NSCB_B, &SC[SC_MUNIQ]);
  hscan3_kernel<<<NSCB_B, 256, 0, stream>>>(BLK, NSCB, PART);

  // === Phase D: sub selection (k=800k) ===
  keys_kernel<<<31250, 256, 0, stream>>>(WARR, att, (const float*)SC, KEYS, ksub, 1);
  run_select(800000u);
  scatter_kernel<<<NBLK_E, 256, 0, stream>>>(KEYS, SC, EQL, SBLK, KIDX, (int*)nullptr, 0);
  build_rows_kernel<<<3297, 256, 0, stream>>>(KIDX, adj_rows, adj_cols, NEWR, NEWC, SROWS_LEN);
  zero_kernel<<<172, 256, 0, stream>>>((uint32_t*)DEG, (long long)NVERT);
  deg_count_kernel<<<3297, 256, 0, stream>>>(NEWR, DEG, SROWS_LEN);
  deg_inv_kernel<<<172, 256, 0, stream>>>(DEG, DINVS);

  // === Phase E: cmp selection (k=800k) ===
  keys_kernel<<<31250, 256, 0, stream>>>(WARR, att, (const float*)SC, KEYS, kcmp, 2);
  run_select(800000u);
  scatter_kernel<<<NBLK_E, 256, 0, stream>>>(KEYS, SC, EQL, SBLK, KIDX, (int*)nullptr, 0);
  build_rows_kernel<<<3297, 256, 0, stream>>>(KIDX, adj_rows, adj_cols, CMPR, CMPC, SROWS_LEN);
  zero_kernel<<<172, 256, 0, stream>>>((uint32_t*)DEG, (long long)NVERT);
  deg_count_kernel<<<3297, 256, 0, stream>>>(CMPR, DEG, SROWS_LEN);
  deg_inv_kernel<<<172, 256, 0, stream>>>(DEG, DINVC);

  // === Phase F: EMIT ALL OUTPUTS (f32, natural return order) ===
  dec_out_kernel<<<NSCB, 256, 0, stream>>>(BMP, BLK, outb);
  dec_pad_kernel<<<65969, 256, 0, stream>>>(outb, SC);
  graph_out_kernel<<<3297, 256, 0, stream>>>(NEWR, NEWC, DINVS, outb, O4, O5, SROWS_LEN);
  graph_out_kernel<<<3297, 256, 0, stream>>>(CMPR, CMPC, DINVC, outb, O6, O7, SROWS_LEN);
  graph_out_kernel<<<15797, 256, 0, stream>>>(ROWS, COLS, DINV, outb, O0, O1, ROWS_LEN);
}

// Round 15
// 5932.557 us; speedup vs baseline: 1.1422x; 1.1422x over previous
//
#include <hip/hip_runtime.h>
#include <stdint.h>

// ============================================================================
// RandomMaskSubgraphs on gfx950. Round 15 (perf; passing since R10).
// R14 post-mortem: setprio(3)+ping-pong REGRESSED sums (3.44->4.65ms) --
// starved staging waves; two variables changed at once. Hierarchical scans
// helped (~0.45ms). This round, ONE variable: revert chain to R13 rotation
// form (no setprio), block 1024->512 so the chain wave shares its SIMD with
// ONE staging wave instead of three (issue-contention hypothesis, clean test).
// ============================================================================
#define PARTITIONABLE 1
#define SUM_LANES 8

#define E_EDGES   8000000
#define NVERT     44000
#define N_EXT     2000000
#define N_NEW     6400000
#define ROWS_LEN  4044000
#define SROWS_LEN 844000
#define DEC_LEN   16888000
#define BMP_WORDS 60500000
#define NSCB      59083
#define NBLK_E    1954
#define NSCB_B    231
#define NBLK_B    8

#define SPAN_EXT  4044000u
#define SPAN_NEW  6000000u

#define O0 0LL
#define O1 8088000LL
#define O2 12132000LL
#define O3 45908000LL
#define O4 62796000LL
#define O5 64484000LL
#define O6 65328000LL
#define O7 67016000LL
#define OUT_TOTAL 67860000

#define SC_SKEEP  0
#define SC_SSUB   1
#define SC_PREFIX 2
#define SC_KPRIME 3
#define SC_T      4
#define SC_M      5
#define SC_EQC    6
#define SC_EQN    7
#define SC_MUNIQ  8
#define SC_HIST   16
#define SC_PART   512

struct TF2 { uint32_t a, b; };

__host__ __device__ __forceinline__ TF2 tf2x32(uint32_t k0, uint32_t k1,
                                               uint32_t c0, uint32_t c1) {
  uint32_t ks2 = k0 ^ k1 ^ 0x1BD11BDAu;
  uint32_t x0 = c0 + k0, x1 = c1 + k1;
#define TFR(r) { x0 += x1; x1 = (x1 << (r)) | (x1 >> (32 - (r))); x1 ^= x0; }
  TFR(13) TFR(15) TFR(26) TFR(6)   x0 += k1;  x1 += ks2 + 1u;
  TFR(17) TFR(29) TFR(16) TFR(24)  x0 += ks2; x1 += k0 + 2u;
  TFR(13) TFR(15) TFR(26) TFR(6)   x0 += k0;  x1 += k1 + 3u;
  TFR(17) TFR(29) TFR(16) TFR(24)  x0 += k1;  x1 += ks2 + 4u;
  TFR(13) TFR(15) TFR(26) TFR(6)   x0 += ks2; x1 += k0 + 5u;
#undef TFR
  TF2 r; r.a = x0; r.b = x1; return r;
}

__device__ __forceinline__ uint32_t rbits(uint2 k, uint32_t i, uint32_t half) {
#if PARTITIONABLE
  TF2 r = tf2x32(k.x, k.y, 0u, i);
  return r.a ^ r.b;
#else
  if (i < half) return tf2x32(k.x, k.y, i, half + i).a;
  return tf2x32(k.x, k.y, i - half, i).b;
#endif
}

__device__ __forceinline__ uint32_t jrandint(uint2 k1, uint2 k2, uint32_t i,
                                             uint32_t half, uint32_t span) {
  uint32_t m1 = 65536u % span;
  uint32_t mult = (m1 * m1) % span;
  uint32_t hb = (mult != 0u) ? rbits(k1, i, half) : 0u;
  uint32_t lb = rbits(k2, i, half);
  uint32_t off = (hb % span) * mult + (lb % span);
  return off % span;
}

__device__ __forceinline__ float unif_from_bits(uint32_t bits) {
#pragma clang fp contract(off)
  float f = __uint_as_float((bits >> 9) | 0x3f800000u) - 1.0f;
  float u = f + 1e-12f;
  return fmaxf(1e-12f, u);
}

__device__ __forceinline__ float xla_logf(float x) {
#pragma clang fp contract(off)
  uint32_t bx = __float_as_uint(x);
  int emm0 = (int)(bx >> 23) - 127;
  float m = __uint_as_float((bx & 0x007fffffu) | 0x3f000000u);
  float e = 1.0f + (float)emm0;
  bool lt = (m < 0.707106781186547524f);
  float tmp1 = lt ? m : 0.0f;
  float t = m - 1.0f;
  e = e - (lt ? 1.0f : 0.0f);
  t = t + tmp1;
  float x2 = t * t;
  float x3 = x2 * t;
  float y, y1, y2;
  y  = t * 7.0376836292e-2f  + -1.1514610310e-1f;
  y1 = t * -1.2420140846e-1f +  1.4249322787e-1f;
  y2 = t * 2.0000714765e-1f  + -2.4999993993e-1f;
  y  = y  * t +  1.1676998740e-1f;
  y1 = y1 * t + -1.6668057665e-1f;
  y2 = y2 * t +  3.3333331174e-1f;
  y = y * x3 + y1;
  y = y * x3 + y2;
  y = y * x3;
  y1 = -2.12194440e-4f * e;
  float tmp2 = 0.5f * x2;
  y = y + y1;
  t = t - tmp2;
  y2 = 0.693359375f * e;
  t = t + y;
  t = t + y2;
  return t;
}

__device__ __forceinline__ float xla_expf(float x) {
#pragma clang fp contract(off)
  x = fminf(x, 88.3762626647950f);
  x = fmaxf(x, -88.3762626647949f);
  float fx = x * 1.44269504088896341f + 0.5f;
  float flr = floorf(fx);
  float t1 = flr * 0.693359375f;
  float t2 = flr * -2.12194440e-4f;
  x = x - t1;
  x = x - t2;
  float z = x * x;
  float y = 1.9875691500e-4f;
  y = y * x + 1.3981999507e-3f;
  y = y * x + 8.3334519073e-3f;
  y = y * x + 4.1665795894e-2f;
  y = y * x + 1.6666665459e-1f;
  y = y * x + 5.0000001201e-1f;
  y = y * z;
  y = y + x;
  y = y + 1.0f;
  int n = (int)flr;
  float p2n = __uint_as_float((uint32_t)(n + 127) << 23);
  return y * p2n;
}

__device__ __forceinline__ uint32_t score_key(float w, float S, float u) {
#pragma clang fp contract(off)
  float p = w / S;
  float lu = xla_logf(u);
  float g = xla_logf(-lu);
  float s = xla_logf(p) - g;
  uint32_t b = __float_as_uint(s);
  return (b & 0x80000000u) ? ~b : (b | 0x80000000u);
}

// ---------------------------------------------------------------------------
__global__ void zero_kernel(uint32_t* p, long long n) {
  long long i = (long long)blockIdx.x * blockDim.x + threadIdx.x;
  long long stride = (long long)gridDim.x * blockDim.x;
  for (; i < n; i += stride) p[i] = 0u;
}

__global__ void sentinel_kernel(float* outb, float code) {
  if (blockIdx.x == 0 && threadIdx.x == 0) outb[0] = code;
}

__global__ void w_kernel(const float* att, float* warr) {
#pragma clang fp contract(off)
  int i = blockIdx.x * 256 + threadIdx.x;
  if (i >= E_EDGES) return;
  float c = fminf(att[i], 3.0f);
  float x = c + 1e-8f;
  warr[i] = 1.0f / xla_expf(x);
}

// Exact-order sums, transposed-LDS pipeline. 512 threads: wave 0 chains,
// 448 staging threads. R13 rotation chain form (known-good).
#define SUMS_CH   16000
#define SUMS_V4   4000
#define PSTRIPE   2004
#define SUMS_B4   10
#define SUMS_NB   50
#define SUMS_NCH  500
#define SUMS_STG  448
__global__ __launch_bounds__(512) void sums_kernel(const float* warr, const float* att, float* scf) {
#pragma clang fp contract(off)
  __shared__ __align__(16) float buf0[8 * PSTRIPE];
  __shared__ __align__(16) float buf1[8 * PSTRIPE];
  __shared__ float lanes[SUM_LANES];
  int t = threadIdx.x;
  int which = blockIdx.x;
  const float4* src4 = (const float4*)(which == 0 ? warr : att);

  if (t >= 64) {
    for (int q = t - 64; q < SUMS_V4; q += SUMS_STG) {
      float4 v = src4[q];
      if (which == 1) {
        v.x = fminf(v.x, 3.0f) + 0.001f;
        v.y = fminf(v.y, 3.0f) + 0.001f;
        v.z = fminf(v.z, 3.0f) + 0.001f;
        v.w = fminf(v.w, 3.0f) + 0.001f;
      }
      int k = q >> 1;
      int s0 = (q & 1) * 4;
      buf0[(s0 + 0) * PSTRIPE + k] = v.x;
      buf0[(s0 + 1) * PSTRIPE + k] = v.y;
      buf0[(s0 + 2) * PSTRIPE + k] = v.z;
      buf0[(s0 + 3) * PSTRIPE + k] = v.w;
    }
  }
  __syncthreads();

  float acc = 0.0f;
  for (int c = 0; c < SUMS_NCH; ++c) {
    float* curb = (c & 1) ? buf1 : buf0;
    float* nxtb = (c & 1) ? buf0 : buf1;
    if (t >= 64) {
      if (c + 1 < SUMS_NCH) {
        const float4* base = src4 + (long long)(c + 1) * SUMS_V4;
        for (int q = t - 64; q < SUMS_V4; q += SUMS_STG) {
          float4 v = base[q];
          if (which == 1) {
            v.x = fminf(v.x, 3.0f) + 0.001f;
            v.y = fminf(v.y, 3.0f) + 0.001f;
            v.z = fminf(v.z, 3.0f) + 0.001f;
            v.w = fminf(v.w, 3.0f) + 0.001f;
          }
          int k = q >> 1;
          int s0 = (q & 1) * 4;
          nxtb[(s0 + 0) * PSTRIPE + k] = v.x;
          nxtb[(s0 + 1) * PSTRIPE + k] = v.y;
          nxtb[(s0 + 2) * PSTRIPE + k] = v.z;
          nxtb[(s0 + 3) * PSTRIPE + k] = v.w;
        }
      }
    } else if (t < SUM_LANES) {
      const float4* stripe4 = (const float4*)(curb + t * PSTRIPE);
      float4 ld[SUMS_B4];
#pragma unroll
      for (int u = 0; u < SUMS_B4; ++u) ld[u] = stripe4[u];
      for (int b = 0; b < SUMS_NB; ++b) {
        float4 nx[SUMS_B4];
        if (b + 1 < SUMS_NB) {
          int boff = (b + 1) * SUMS_B4;
#pragma unroll
          for (int u = 0; u < SUMS_B4; ++u) nx[u] = stripe4[boff + u];
        }
#pragma unroll
        for (int u = 0; u < SUMS_B4; ++u) {
          acc += ld[u].x; acc += ld[u].y; acc += ld[u].z; acc += ld[u].w;
        }
        if (b + 1 < SUMS_NB) {
#pragma unroll
          for (int u = 0; u < SUMS_B4; ++u) ld[u] = nx[u];
        }
      }
    }
    __syncthreads();
  }

  if (t < SUM_LANES) lanes[t] = acc;
  __syncthreads();
  if (t == 0) {
    float v[SUM_LANES];
    for (int q = 0; q < SUM_LANES; ++q) v[q] = lanes[q];
    int w = SUM_LANES;
    while (w > 1) { int h = w >> 1; for (int q = 0; q < h; ++q) v[q] = v[q] + v[q + h]; w = h; }
    scf[which] = v[0];
  }
}

__global__ void keys_kernel(const float* warr, const float* att, const float* scf,
                            uint32_t* keys, uint2 kk, int mode) {
  int i = blockIdx.x * 256 + threadIdx.x;
  if (i >= E_EDGES) return;
  float S = (mode == 1) ? scf[SC_SSUB] : scf[SC_SKEEP];
  float w;
  if (mode == 1) { float a = att[i]; w = fminf(a, 3.0f) + 0.001f; }
  else w = warr[i];
  uint32_t b = rbits(kk, (uint32_t)i, 4000000u);
  keys[i] = score_key(w, S, unif_from_bits(b));
}

__global__ void sel_reset_kernel(uint32_t* sc, uint32_t k) {
  int t = threadIdx.x;
  sc[SC_HIST + t] = 0u;
  if (t == 0) { sc[SC_PREFIX] = 0u; sc[SC_KPRIME] = k; sc[SC_EQC] = 0u; sc[SC_EQN] = 0u; }
}

__global__ void sel_hist_kernel(const uint32_t* keys, uint32_t* sc, int round) {
  __shared__ uint32_t h[256];
  int t = threadIdx.x;
  h[t] = 0u;
  __syncthreads();
  uint32_t pref = sc[SC_PREFIX];
  int shift = 24 - 8 * round;
  uint32_t maskHi = (round == 0) ? 0u : (0xFFFFFFFFu << (shift + 8));
  int i = blockIdx.x * 4096 + t;
#pragma unroll
  for (int it = 0; it < 16; ++it, i += 256) {
    if (i < E_EDGES) {
      uint32_t key = keys[i];
      if (((key ^ pref) & maskHi) == 0u) atomicAdd(&h[(key >> shift) & 0xffu], 1u);
    }
  }
  __syncthreads();
  if (h[t]) atomicAdd(&sc[SC_HIST + t], h[t]);
}

__global__ void sel_pick_kernel(uint32_t* sc, int round) {
  if (blockIdx.x != 0 || threadIdx.x != 0) return;
  uint32_t kprime = sc[SC_KPRIME];
  int shift = 24 - 8 * round;
  uint32_t cum = 0; uint32_t bsel = 0;
  for (int b = 255; b >= 0; --b) {
    uint32_t c = sc[SC_HIST + b];
    if (cum + c >= kprime) { bsel = (uint32_t)b; break; }
    cum += c;
  }
  sc[SC_PREFIX] |= bsel << shift;
  sc[SC_KPRIME] = kprime - cum;
  for (int b = 0; b < 256; ++b) sc[SC_HIST + b] = 0u;
  if (round == 3) { sc[SC_T] = sc[SC_PREFIX]; sc[SC_M] = sc[SC_KPRIME]; }
}

__global__ void eq_collect_kernel(const uint32_t* keys, uint32_t* sc, uint32_t* eql) {
  int i = blockIdx.x * 256 + threadIdx.x;
  if (i >= E_EDGES) return;
  if (keys[i] == sc[SC_T]) {
    uint32_t p = atomicAdd(&sc[SC_EQC], 1u);
    if (p < 4096u) eql[p] = (uint32_t)i;
  }
}

__global__ void eq_sort_kernel(uint32_t* sc, uint32_t* eql) {
  if (blockIdx.x != 0 || threadIdx.x != 0) return;
  uint32_t n = sc[SC_EQC]; if (n > 4096u) n = 4096u;
  sc[SC_EQN] = n;
  for (uint32_t a = 1; a < n; ++a) {
    uint32_t v = eql[a]; uint32_t b = a;
    while (b > 0 && eql[b - 1] > v) { eql[b] = eql[b - 1]; --b; }
    eql[b] = v;
  }
}

__device__ __forceinline__ int keep_flag(uint32_t key, uint32_t T, uint32_t m,
                                         const uint32_t* eql, uint32_t eqn, uint32_t i) {
  if (key > T) return 1;
  if (key != T) return 0;
  uint32_t lo = 0, hi = eqn;
  while (lo < hi) { uint32_t mid = (lo + hi) >> 1; if (eql[mid] < i) lo = mid + 1; else hi = mid; }
  return (lo < m) ? 1 : 0;
}

__global__ void cnt_flags_kernel(const uint32_t* keys, const uint32_t* sc,
                                 const uint32_t* eql, uint32_t* sblk) {
  __shared__ uint32_t s[256];
  int t = threadIdx.x;
  uint32_t T = sc[SC_T], m = sc[SC_M], eqn = sc[SC_EQN];
  int base = blockIdx.x * 4096 + t * 16;
  uint32_t cnt = 0;
#pragma unroll
  for (int j = 0; j < 16; ++j) {
    int i = base + j;
    if (i < E_EDGES) cnt += keep_flag(keys[i], T, m, eql, eqn, (uint32_t)i);
  }
  s[t] = cnt;
  __syncthreads();
  for (int off = 128; off > 0; off >>= 1) { if (t < off) s[t] += s[t + off]; __syncthreads(); }
  if (t == 0) sblk[blockIdx.x] = s[0];
}

__global__ void scan_small_kernel(uint32_t* a, int n, uint32_t* totalOut) {
  __shared__ uint32_t s[256];
  int t = threadIdx.x;
  uint32_t carry = 0;
  for (int base = 0; base < n; base += 256) {
    int idx = base + t;
    uint32_t v = (idx < n) ? a[idx] : 0u;
    s[t] = v;
    __syncthreads();
    for (int off = 1; off < 256; off <<= 1) {
      uint32_t x = 0; if (t >= off) x = s[t - off];
      __syncthreads();
      if (t >= off) s[t] += x;
      __syncthreads();
    }
    uint32_t incl = s[t];
    uint32_t tot = s[255];
    if (idx < n) a[idx] = incl - v + carry;
    carry += tot;
    __syncthreads();
  }
  if (t == 0 && totalOut) *totalOut = carry;
}

__global__ void hscan1_kernel(uint32_t* a, int n, uint32_t* part) {
  __shared__ uint32_t s[256];
  int t = threadIdx.x;
  int idx = blockIdx.x * 256 + t;
  uint32_t v = (idx < n) ? a[idx] : 0u;
  s[t] = v;
  __syncthreads();
  for (int off = 1; off < 256; off <<= 1) {
    uint32_t x = 0; if (t >= off) x = s[t - off];
    __syncthreads();
    if (t >= off) s[t] += x;
    __syncthreads();
  }
  if (idx < n) a[idx] = s[t] - v;
  if (t == 255) part[blockIdx.x] = s[255];
}

__global__ void hscan3_kernel(uint32_t* a, int n, const uint32_t* part) {
  int idx = blockIdx.x * 256 + threadIdx.x;
  if (idx < n) a[idx] += part[blockIdx.x];
}

__global__ void scatter_kernel(const uint32_t* keys, const uint32_t* sc, const uint32_t* eql,
                               const uint32_t* sblk, int* kidx, int* didx, int writeDrop) {
  __shared__ uint32_t s[256];
  int t = threadIdx.x;
  uint32_t T = sc[SC_T], m = sc[SC_M], eqn = sc[SC_EQN];
  int base = blockIdx.x * 4096 + t * 16;
  uint32_t fbits = 0, cnt = 0;
#pragma unroll
  for (int j = 0; j < 16; ++j) {
    int i = base + j; int f = 0;
    if (i < E_EDGES) f = keep_flag(keys[i], T, m, eql, eqn, (uint32_t)i);
    fbits |= ((uint32_t)f) << j; cnt += (uint32_t)f;
  }
  s[t] = cnt;
  __syncthreads();
  for (int off = 1; off < 256; off <<= 1) {
    uint32_t x = 0; if (t >= off) x = s[t - off];
    __syncthreads();
    if (t >= off) s[t] += x;
    __syncthreads();
  }
  uint32_t run = sblk[blockIdx.x] + (s[t] - cnt);
  for (int j = 0; j < 16; ++j) {
    int i = base + j;
    if (i >= E_EDGES) break;
    if ((fbits >> j) & 1u) {
      if (run < 4000000u) kidx[run] = i;
      run++;
    } else if (writeDrop) {
      uint32_t d = (uint32_t)i - run;
      if (d < 4000000u) didx[d] = i;
    }
  }
}

__global__ void build_rows_kernel(const int* kidx, const int* ar, const int* ac,
                                  int* rows, int* cols, int total) {
  int i = blockIdx.x * 256 + threadIdx.x;
  if (i >= total) return;
  if (i < NVERT) { rows[i] = i; cols[i] = i; }
  else {
    int j = kidx[i - NVERT];
    j = (j < 0) ? 0 : (j >= E_EDGES ? E_EDGES - 1 : j);
    rows[i] = ar[j]; cols[i] = ac[j];
  }
}

__global__ void deg_count_kernel(const int* rows, int* deg, int len) {
  int i = blockIdx.x * 256 + threadIdx.x;
  if (i >= len) return;
  int r = rows[i];
  r = (r < 0) ? 0 : (r >= NVERT ? NVERT - 1 : r);
  atomicAdd(&deg[r], 1);
}

__global__ void deg_inv_kernel(const int* deg, float* dinv) {
  int i = blockIdx.x * 256 + threadIdx.x;
  if (i >= NVERT) return;
  int d = deg[i];
  dinv[i] = (d > 0) ? (float)(1.0 / sqrt((double)d)) : 0.0f;
}

__global__ void graph_out_kernel(const int* rows, const int* cols, const float* dinv,
                                 float* outb, long long idxOff, long long valOff, int len) {
#pragma clang fp contract(off)
  int i = blockIdx.x * 256 + threadIdx.x;
  if (i >= len) return;
  int r = rows[i], c = cols[i];
  r = (r < 0) ? 0 : (r >= NVERT ? NVERT - 1 : r);
  c = (c < 0) ? 0 : (c >= NVERT ? NVERT - 1 : c);
  outb[idxOff + i] = (float)r;
  outb[idxOff + len + i] = (float)c;
  outb[valOff + i] = dinv[r] * dinv[c];
}

__global__ void newrc_kernel(const int* rows, const int* cols, const int* didx,
                             const int* ar, const int* ac, int* newr, int* newc,
                             uint2 knr1, uint2 knr2, uint2 knc1, uint2 knc2,
                             uint2 ker1, uint2 ker2, uint2 kec1, uint2 kec2) {
  int i = blockIdx.x * 256 + threadIdx.x;
  if (i >= N_NEW) return;
  uint32_t nr = jrandint(knr1, knr2, (uint32_t)i, 3200000u, SPAN_NEW);
  int v;
  if (nr < (uint32_t)N_EXT) {
    uint32_t e = jrandint(ker1, ker2, nr, 1000000u, SPAN_EXT);
    v = rows[e];
  } else {
    int d = didx[nr - (uint32_t)N_EXT];
    d = (d < 0) ? 0 : (d >= E_EDGES ? E_EDGES - 1 : d);
    v = ar[d];
  }
  newr[i] = v;
  uint32_t nc = jrandint(knc1, knc2, (uint32_t)i, 3200000u, SPAN_NEW);
  if (nc < (uint32_t)N_EXT) {
    uint32_t e = jrandint(kec1, kec2, nc, 1000000u, SPAN_EXT);
    v = cols[e];
  } else {
    int d = didx[nc - (uint32_t)N_EXT];
    d = (d < 0) ? 0 : (d >= E_EDGES ? E_EDGES - 1 : d);
    v = ac[d];
  }
  newc[i] = v;
}

__global__ void bmp_mark_kernel(const int* newr, const int* newc,
                                const int* rows, const int* cols, uint32_t* bmp) {
  int i = blockIdx.x * 256 + threadIdx.x;
  if (i >= DEC_LEN) return;
  int r, c;
  if (i < N_NEW) { r = newr[i]; c = newc[i]; }
  else if (i < 2 * N_NEW) { r = newc[i - N_NEW]; c = newr[i - N_NEW]; }
  else if (i < 2 * N_NEW + NVERT) { r = i - 2 * N_NEW; c = r; }
  else { int q = i - (2 * N_NEW + NVERT); r = rows[q]; c = cols[q]; }
  r = (r < 0) ? 0 : (r >= NVERT ? NVERT - 1 : r);
  c = (c < 0) ? 0 : (c >= NVERT ? NVERT - 1 : c);
  uint32_t h = (uint32_t)r * 44000u + (uint32_t)c;
  atomicOr(&bmp[h >> 5], 1u << (h & 31u));
}

__global__ void bmp_cnt_kernel(const uint32_t* bmp, uint32_t* blk) {
  __shared__ uint32_t s[256];
  int t = threadIdx.x;
  long long wbase = (long long)blockIdx.x * 1024 + (long long)t * 4;
  uint32_t c = 0;
#pragma unroll
  for (int j = 0; j < 4; ++j) {
    long long w = wbase + j;
    if (w < (long long)BMP_WORDS) c += __popc(bmp[w]);
  }
  s[t] = c;
  __syncthreads();
  for (int off = 128; off > 0; off >>= 1) { if (t < off) s[t] += s[t + off]; __syncthreads(); }
  if (t == 0) blk[blockIdx.x] = s[0];
}

__global__ void dec_out_kernel(const uint32_t* bmp, const uint32_t* blk, float* outb) {
  __shared__ uint32_t s[256];
  int t = threadIdx.x;
  long long wbase = (long long)blockIdx.x * 1024 + (long long)t * 4;
  uint32_t cn[4]; uint32_t tot = 0;
#pragma unroll
  for (int j = 0; j < 4; ++j) {
    long long w = wbase + j;
    cn[j] = (w < (long long)BMP_WORDS) ? (uint32_t)__popc(bmp[w]) : 0u;
    tot += cn[j];
  }
  s[t] = tot;
  __syncthreads();
  for (int off = 1; off < 256; off <<= 1) {
    uint32_t x = 0; if (t >= off) x = s[t - off];
    __syncthreads();
    if (t >= off) s[t] += x;
    __syncthreads();
  }
  uint32_t pos = blk[blockIdx.x] + (s[t] - tot);
  for (int j = 0; j < 4; ++j) {
    long long w = wbase + j;
    if (w >= (long long)BMP_WORDS) break;
    uint32_t word = bmp[w];
    while (word) {
      int b = __ffs(word) - 1;
      word &= word - 1u;
      uint32_t v = (uint32_t)w * 32u + (uint32_t)b;
      uint32_t ur = v / 44000u;
      uint32_t uc = v - ur * 44000u;
      if (pos < (uint32_t)DEC_LEN) {
        outb[O2 + pos] = (float)ur;
        outb[O2 + DEC_LEN + pos] = (float)uc;
        outb[O3 + pos] = 1.0f;
      }
      pos++;
    }
  }
}

__global__ void dec_pad_kernel(float* outb, const uint32_t* sc) {
  int p = blockIdx.x * 256 + threadIdx.x;
  if (p >= DEC_LEN) return;
  if ((uint32_t)p >= sc[SC_MUNIQ]) {
    outb[O2 + p] = 0.0f; outb[O2 + DEC_LEN + p] = 0.0f; outb[O3 + p] = 0.0f;
  }
}

// ---------------------------------------------------------------------------
static void jsplit2(uint2 k, uint2& k1, uint2& k2) {
#if PARTITIONABLE
  TF2 a = tf2x32(k.x, k.y, 0u, 0u), b = tf2x32(k.x, k.y, 0u, 1u);
  k1.x = a.a; k1.y = a.b; k2.x = b.a; k2.y = b.b;
#else
  TF2 a = tf2x32(k.x, k.y, 0u, 2u), b = tf2x32(k.x, k.y, 1u, 3u);
  k1.x = a.a; k1.y = b.a; k2.x = a.b; k2.y = b.b;
#endif
}

extern "C" void kernel_launch(void* const* d_in, const int* in_sizes, int n_in,
                              void* d_out, int out_size, void* d_ws, size_t ws_size,
                              hipStream_t stream) {
  float* outb = (float*)d_out;

  if (out_size != OUT_TOTAL) {
    sentinel_kernel<<<1, 64, 0, stream>>>(outb, 16777216.0f);
    return;
  }
  if (n_in < 4 || in_sizes[0] != E_EDGES || in_sizes[3] != E_EDGES) {
    sentinel_kernel<<<1, 64, 0, stream>>>(outb, 20971520.0f);
    return;
  }
  if (ws_size < 429300000ULL) {
    sentinel_kernel<<<1, 64, 0, stream>>>(outb, 25165824.0f);
    return;
  }

  const int* adj_rows = (const int*)d_in[0];
  const int* adj_cols = (const int*)d_in[1];
  const float* att = (const float*)d_in[3];
  char* ws = (char*)d_ws;

  uint32_t* KEYS  = (uint32_t*)(ws + 0LL);
  float*    WARR  = (float*)(ws + 32000000LL);
  int*      KIDX  = (int*)(ws + 64000000LL);
  int*      DIDX  = (int*)(ws + 80000000LL);
  int*      ROWS  = (int*)(ws + 96000000LL);
  int*      COLS  = (int*)(ws + 112176000LL);
  int*      NEWR  = (int*)(ws + 128352000LL);
  int*      NEWC  = (int*)(ws + 153952000LL);
  uint32_t* BMP   = (uint32_t*)(ws + 179552000LL);
  uint32_t* BLK   = (uint32_t*)(ws + 421552000LL);
  int*      DEG   = (int*)(ws + 421788544LL);
  float*    DINV  = (float*)(ws + 421964544LL);
  uint32_t* SBLK  = (uint32_t*)(ws + 422140544LL);
  uint32_t* SC    = (uint32_t*)(ws + 422148736LL);
  uint32_t* EQL   = (uint32_t*)(ws + 422152832LL);
  int*      CMPR  = (int*)(ws + 422169216LL);
  int*      CMPC  = (int*)(ws + 425545216LL);
  float*    DINVS = (float*)(ws + 428921216LL);
  float*    DINVC = (float*)(ws + 429097216LL);
  uint32_t* PART  = SC + SC_PART;

  TF2 K[7];
#if PARTITIONABLE
  for (int i = 0; i < 7; ++i) K[i] = tf2x32(0u, 42u, 0u, (uint32_t)i);
#else
  {
    TF2 T_[7];
    for (int i = 0; i < 7; ++i) T_[i] = tf2x32(0u, 42u, (uint32_t)i, (uint32_t)(7 + i));
    K[0].a = T_[0].a; K[0].b = T_[1].a;
    K[1].a = T_[2].a; K[1].b = T_[3].a;
    K[2].a = T_[4].a; K[2].b = T_[5].a;
    K[3].a = T_[6].a; K[3].b = T_[0].b;
    K[4].a = T_[1].b; K[4].b = T_[2].b;
    K[5].a = T_[3].b; K[5].b = T_[4].b;
    K[6].a = T_[5].b; K[6].b = T_[6].b;
  }
#endif
  uint2 kkeep, ker, kec, knr, knc, ksub, kcmp;
  kkeep.x = K[0].a; kkeep.y = K[0].b;
  ker.x = K[1].a; ker.y = K[1].b;
  kec.x = K[2].a; kec.y = K[2].b;
  knr.x = K[3].a; knr.y = K[3].b;
  knc.x = K[4].a; knc.y = K[4].b;
  ksub.x = K[5].a; ksub.y = K[5].b;
  kcmp.x = K[6].a; kcmp.y = K[6].b;
  uint2 ker1, ker2, kec1, kec2, knr1, knr2, knc1, knc2;
  jsplit2(ker, ker1, ker2); jsplit2(kec, kec1, kec2);
  jsplit2(knr, knr1, knr2); jsplit2(knc, knc1, knc2);

  // === Phase A: init ===
  zero_kernel<<<4096, 256, 0, stream>>>(BMP, (long long)BMP_WORDS);
  zero_kernel<<<1, 256, 0, stream>>>(SC, 1024LL);
  zero_kernel<<<2048, 256, 0, stream>>>((uint32_t*)KIDX, 8000000LL);
  w_kernel<<<31250, 256, 0, stream>>>(att, WARR);
  sums_kernel<<<2, 512, 0, stream>>>(WARR, att, (float*)SC);

  auto run_select = [&](uint32_t kcount) {
    sel_reset_kernel<<<1, 256, 0, stream>>>(SC, kcount);
    for (int r = 0; r < 4; ++r) {
      sel_hist_kernel<<<NBLK_E, 256, 0, stream>>>(KEYS, SC, r);
      sel_pick_kernel<<<1, 64, 0, stream>>>(SC, r);
    }
    eq_collect_kernel<<<31250, 256, 0, stream>>>(KEYS, SC, EQL);
    eq_sort_kernel<<<1, 64, 0, stream>>>(SC, EQL);
    cnt_flags_kernel<<<NBLK_E, 256, 0, stream>>>(KEYS, SC, EQL, SBLK);
    hscan1_kernel<<<NBLK_B, 256, 0, stream>>>(SBLK, NBLK_E, PART);
    scan_small_kernel<<<1, 256, 0, stream>>>(PART, NBLK_B, (uint32_t*)nullptr);
    hscan3_kernel<<<NBLK_B, 256, 0, stream>>>(SBLK, NBLK_E, PART);
  };

  // === Phase B: encoder keep selection (k=4M) -> ROWS/COLS/DINV ===
  keys_kernel<<<31250, 256, 0, stream>>>(WARR, att, (const float*)SC, KEYS, kkeep, 0);
  run_select(4000000u);
  scatter_kernel<<<NBLK_E, 256, 0, stream>>>(KEYS, SC, EQL, SBLK, KIDX, DIDX, 1);
  build_rows_kernel<<<15797, 256, 0, stream>>>(KIDX, adj_rows, adj_cols, ROWS, COLS, ROWS_LEN);
  zero_kernel<<<172, 256, 0, stream>>>((uint32_t*)DEG, (long long)NVERT);
  deg_count_kernel<<<15797, 256, 0, stream>>>(ROWS, DEG, ROWS_LEN);
  deg_inv_kernel<<<172, 256, 0, stream>>>(DEG, DINV);

  // === Phase C: decoder rewire + bitmap unique -> BMP/BLK/MUNIQ ===
  newrc_kernel<<<25000, 256, 0, stream>>>(ROWS, COLS, DIDX, adj_rows, adj_cols, NEWR, NEWC,
                                          knr1, knr2, knc1, knc2, ker1, ker2, kec1, kec2);
  bmp_mark_kernel<<<65969, 256, 0, stream>>>(NEWR, NEWC, ROWS, COLS, BMP);
  bmp_cnt_kernel<<<NSCB, 256, 0, stream>>>(BMP, BLK);
  hscan1_kernel<<<NSCB_B, 256, 0, stream>>>(BLK, NSCB, PART);
  scan_small_kernel<<<1, 256, 0, stream>>>(PART, NSCB_B, &SC[SC_MUNIQ]);
  hscan3_kernel<<<NSCB_B, 256, 0, stream>>>(BLK, NSCB, PART);

  // === Phase D: sub selection (k=800k) ===
  keys_kernel<<<31250, 256, 0, stream>>>(WARR, att, (const float*)SC, KEYS, ksub, 1);
  run_select(800000u);
  scatter_kernel<<<NBLK_E, 256, 0, stream>>>(KEYS, SC, EQL, SBLK, KIDX, (int*)nullptr, 0);
  build_rows_kernel<<<3297, 256, 0, stream>>>(KIDX, adj_rows, adj_cols, NEWR, NEWC, SROWS_LEN);
  zero_kernel<<<172, 256, 0, stream>>>((uint32_t*)DEG, (long long)NVERT);
  deg_count_kernel<<<3297, 256, 0, stream>>>(NEWR, DEG, SROWS_LEN);
  deg_inv_kernel<<<172, 256, 0, stream>>>(DEG, DINVS);

  // === Phase E: cmp selection (k=800k) ===
  keys_kernel<<<31250, 256, 0, stream>>>(WARR, att, (const float*)SC, KEYS, kcmp, 2);
  run_select(800000u);
  scatter_kernel<<<NBLK_E, 256, 0, stream>>>(KEYS, SC, EQL, SBLK, KIDX, (int*)nullptr, 0);
  build_rows_kernel<<<3297, 256, 0, stream>>>(KIDX, adj_rows, adj_cols, CMPR, CMPC, SROWS_LEN);
  zero_kernel<<<172, 256, 0, stream>>>((uint32_t*)DEG, (long long)NVERT);
  deg_count_kernel<<<3297, 256, 0, stream>>>(CMPR, DEG, SROWS_LEN);
  deg_inv_kernel<<<172, 256, 0, stream>>>(DEG, DINVC);

  // === Phase F: EMIT ALL OUTPUTS (f32, natural return order) ===
  dec_out_kernel<<<NSCB, 256, 0, stream>>>(BMP, BLK, outb);
  dec_pad_kernel<<<65969, 256, 0, stream>>>(outb, SC);
  graph_out_kernel<<<3297, 256, 0, stream>>>(NEWR, NEWC, DINVS, outb, O4, O5, SROWS_LEN);
  graph_out_kernel<<<3297, 256, 0, stream>>>(CMPR, CMPC, DINVC, outb, O6, O7, SROWS_LEN);
  graph_out_kernel<<<15797, 256, 0, stream>>>(ROWS, COLS, DINV, outb, O0, O1, ROWS_LEN);
}

// Round 16
// 5639.409 us; speedup vs baseline: 1.2015x; 1.0520x over previous
//
#include <hip/hip_runtime.h>
#include <stdint.h>

// ============================================================================
// RandomMaskSubgraphs on gfx950. Round 16 (perf; passing since R10).
// R15 post-mortem: sums invariant across 8/16 waves -> chain is at its
// structural floor (dep-add ~5.4cyc + b128 ~12cyc; ~97% of floor). Levers:
// (1) MEGA-DISPATCH: fuse BMP/KIDX zeros + S-independent Gumbel precompute
//     (G=log(-log(u)), 3 key sets) into the sums launch as high-block-ID
//     classes -- hidden under sums' 3.5ms window (sums uses only 2 CUs).
// (2) sel_pick: 256 serial dependent global reads -> parallel LDS scan.
// (3) keys reads precomputed G (1 log instead of 3+threefry) when ws allows.
// ============================================================================
#define PARTITIONABLE 1
#define SUM_LANES 8

#define E_EDGES   8000000
#define NVERT     44000
#define N_EXT     2000000
#define N_NEW     6400000
#define ROWS_LEN  4044000
#define SROWS_LEN 844000
#define DEC_LEN   16888000
#define BMP_WORDS 60500000
#define NSCB      59083
#define NBLK_E    1954
#define NSCB_B    231
#define NBLK_B    8

#define SPAN_EXT  4044000u
#define SPAN_NEW  6000000u

#define O0 0LL
#define O1 8088000LL
#define O2 12132000LL
#define O3 45908000LL
#define O4 62796000LL
#define O5 64484000LL
#define O6 65328000LL
#define O7 67016000LL
#define OUT_TOTAL 67860000

#define SC_SKEEP  0
#define SC_SSUB   1
#define SC_PREFIX 2
#define SC_KPRIME 3
#define SC_T      4
#define SC_M      5
#define SC_EQC    6
#define SC_EQN    7
#define SC_MUNIQ  8
#define SC_HIST   16
#define SC_PART   512

// mega-dispatch block classes
#define MB_SUMS   2
#define MB_ZBMP   4096
#define MB_ZKD    64
#define MB_G      46875    // 24,000,000 / 512
#define GUM_OFF   429306112LL
#define WS_NEED_G 525306112ULL

struct TF2 { uint32_t a, b; };

__host__ __device__ __forceinline__ TF2 tf2x32(uint32_t k0, uint32_t k1,
                                               uint32_t c0, uint32_t c1) {
  uint32_t ks2 = k0 ^ k1 ^ 0x1BD11BDAu;
  uint32_t x0 = c0 + k0, x1 = c1 + k1;
#define TFR(r) { x0 += x1; x1 = (x1 << (r)) | (x1 >> (32 - (r))); x1 ^= x0; }
  TFR(13) TFR(15) TFR(26) TFR(6)   x0 += k1;  x1 += ks2 + 1u;
  TFR(17) TFR(29) TFR(16) TFR(24)  x0 += ks2; x1 += k0 + 2u;
  TFR(13) TFR(15) TFR(26) TFR(6)   x0 += k0;  x1 += k1 + 3u;
  TFR(17) TFR(29) TFR(16) TFR(24)  x0 += k1;  x1 += ks2 + 4u;
  TFR(13) TFR(15) TFR(26) TFR(6)   x0 += ks2; x1 += k0 + 5u;
#undef TFR
  TF2 r; r.a = x0; r.b = x1; return r;
}

__device__ __forceinline__ uint32_t rbits(uint2 k, uint32_t i, uint32_t half) {
#if PARTITIONABLE
  TF2 r = tf2x32(k.x, k.y, 0u, i);
  return r.a ^ r.b;
#else
  if (i < half) return tf2x32(k.x, k.y, i, half + i).a;
  return tf2x32(k.x, k.y, i - half, i).b;
#endif
}

__device__ __forceinline__ uint32_t jrandint(uint2 k1, uint2 k2, uint32_t i,
                                             uint32_t half, uint32_t span) {
  uint32_t m1 = 65536u % span;
  uint32_t mult = (m1 * m1) % span;
  uint32_t hb = (mult != 0u) ? rbits(k1, i, half) : 0u;
  uint32_t lb = rbits(k2, i, half);
  uint32_t off = (hb % span) * mult + (lb % span);
  return off % span;
}

__device__ __forceinline__ float unif_from_bits(uint32_t bits) {
#pragma clang fp contract(off)
  float f = __uint_as_float((bits >> 9) | 0x3f800000u) - 1.0f;
  float u = f + 1e-12f;
  return fmaxf(1e-12f, u);
}

__device__ __forceinline__ float xla_logf(float x) {
#pragma clang fp contract(off)
  uint32_t bx = __float_as_uint(x);
  int emm0 = (int)(bx >> 23) - 127;
  float m = __uint_as_float((bx & 0x007fffffu) | 0x3f000000u);
  float e = 1.0f + (float)emm0;
  bool lt = (m < 0.707106781186547524f);
  float tmp1 = lt ? m : 0.0f;
  float t = m - 1.0f;
  e = e - (lt ? 1.0f : 0.0f);
  t = t + tmp1;
  float x2 = t * t;
  float x3 = x2 * t;
  float y, y1, y2;
  y  = t * 7.0376836292e-2f  + -1.1514610310e-1f;
  y1 = t * -1.2420140846e-1f +  1.4249322787e-1f;
  y2 = t * 2.0000714765e-1f  + -2.4999993993e-1f;
  y  = y  * t +  1.1676998740e-1f;
  y1 = y1 * t + -1.6668057665e-1f;
  y2 = y2 * t +  3.3333331174e-1f;
  y = y * x3 + y1;
  y = y * x3 + y2;
  y = y * x3;
  y1 = -2.12194440e-4f * e;
  float tmp2 = 0.5f * x2;
  y = y + y1;
  t = t - tmp2;
  y2 = 0.693359375f * e;
  t = t + y;
  t = t + y2;
  return t;
}

__device__ __forceinline__ float xla_expf(float x) {
#pragma clang fp contract(off)
  x = fminf(x, 88.3762626647950f);
  x = fmaxf(x, -88.3762626647949f);
  float fx = x * 1.44269504088896341f + 0.5f;
  float flr = floorf(fx);
  float t1 = flr * 0.693359375f;
  float t2 = flr * -2.12194440e-4f;
  x = x - t1;
  x = x - t2;
  float z = x * x;
  float y = 1.9875691500e-4f;
  y = y * x + 1.3981999507e-3f;
  y = y * x + 8.3334519073e-3f;
  y = y * x + 4.1665795894e-2f;
  y = y * x + 1.6666665459e-1f;
  y = y * x + 5.0000001201e-1f;
  y = y * z;
  y = y + x;
  y = y + 1.0f;
  int n = (int)flr;
  float p2n = __uint_as_float((uint32_t)(n + 127) << 23);
  return y * p2n;
}

__device__ __forceinline__ uint32_t orderkey(float s) {
  uint32_t b = __float_as_uint(s);
  return (b & 0x80000000u) ? ~b : (b | 0x80000000u);
}

__device__ __forceinline__ uint32_t score_key(float w, float S, float u) {
#pragma clang fp contract(off)
  float p = w / S;
  float lu = xla_logf(u);
  float g = xla_logf(-lu);
  float s = xla_logf(p) - g;
  return orderkey(s);
}

// ---------------------------------------------------------------------------
__global__ void zero_kernel(uint32_t* p, long long n) {
  long long i = (long long)blockIdx.x * blockDim.x + threadIdx.x;
  long long stride = (long long)gridDim.x * blockDim.x;
  for (; i < n; i += stride) p[i] = 0u;
}

__global__ void sentinel_kernel(float* outb, float code) {
  if (blockIdx.x == 0 && threadIdx.x == 0) outb[0] = code;
}

__global__ void w_kernel(const float* att, float* warr) {
#pragma clang fp contract(off)
  int i = blockIdx.x * 256 + threadIdx.x;
  if (i >= E_EDGES) return;
  float c = fminf(att[i], 3.0f);
  float x = c + 1e-8f;
  warr[i] = 1.0f / xla_expf(x);
}

// Mega phase-A kernel: blocks 0,1 = exact-order sums (R15 form, unchanged);
// next 4096 = BMP zero; next 64 = KIDX/DIDX zero; rest = Gumbel precompute.
#define SUMS_CH   16000
#define SUMS_V4   4000
#define PSTRIPE   2004
#define SUMS_B4   10
#define SUMS_NB   50
#define SUMS_NCH  500
#define SUMS_STG  448
__global__ __launch_bounds__(512) void phaseA_kernel(const float* warr, const float* att,
                                                     float* scf, uint32_t* bmp,
                                                     uint32_t* kdzero, float* gum,
                                                     uint2 kkeep, uint2 ksub, uint2 kcmp) {
#pragma clang fp contract(off)
  __shared__ __align__(16) float buf0[8 * PSTRIPE];
  __shared__ __align__(16) float buf1[8 * PSTRIPE];
  __shared__ float lanes[SUM_LANES];
  int t = threadIdx.x;
  int blk = blockIdx.x;

  if (blk >= MB_SUMS) {
    if (blk < MB_SUMS + MB_ZBMP) {
      // BMP zero: 2,097,152 threads over 60.5M words
      int zid = (blk - MB_SUMS) * 512 + t;
      for (long long w = zid; w < (long long)BMP_WORDS; w += (long long)MB_ZBMP * 512)
        bmp[w] = 0u;
    } else if (blk < MB_SUMS + MB_ZBMP + MB_ZKD) {
      // KIDX+DIDX zero: 8M words
      int zid = (blk - MB_SUMS - MB_ZBMP) * 512 + t;
      for (long long w = zid; w < 8000000LL; w += (long long)MB_ZKD * 512)
        kdzero[w] = 0u;
    } else {
      // Gumbel precompute: gi in [0, 24M), set = gi/8M
      long long gi = (long long)(blk - MB_SUMS - MB_ZBMP - MB_ZKD) * 512 + t;
      uint32_t set = (uint32_t)(gi / 8000000LL);
      uint32_t i = (uint32_t)(gi - (long long)set * 8000000LL);
      uint2 kk = (set == 0) ? kkeep : ((set == 1) ? ksub : kcmp);
      uint32_t b = rbits(kk, i, 4000000u);
      float u = unif_from_bits(b);
      gum[gi] = xla_logf(-xla_logf(u));
    }
    return;
  }

  // --- sums blocks (0,1), identical to R15 ---
  int which = blk;
  const float4* src4 = (const float4*)(which == 0 ? warr : att);

  if (t >= 64) {
    for (int q = t - 64; q < SUMS_V4; q += SUMS_STG) {
      float4 v = src4[q];
      if (which == 1) {
        v.x = fminf(v.x, 3.0f) + 0.001f;
        v.y = fminf(v.y, 3.0f) + 0.001f;
        v.z = fminf(v.z, 3.0f) + 0.001f;
        v.w = fminf(v.w, 3.0f) + 0.001f;
      }
      int k = q >> 1;
      int s0 = (q & 1) * 4;
      buf0[(s0 + 0) * PSTRIPE + k] = v.x;
      buf0[(s0 + 1) * PSTRIPE + k] = v.y;
      buf0[(s0 + 2) * PSTRIPE + k] = v.z;
      buf0[(s0 + 3) * PSTRIPE + k] = v.w;
    }
  }
  __syncthreads();

  float acc = 0.0f;
  for (int c = 0; c < SUMS_NCH; ++c) {
    float* curb = (c & 1) ? buf1 : buf0;
    float* nxtb = (c & 1) ? buf0 : buf1;
    if (t >= 64) {
      if (c + 1 < SUMS_NCH) {
        const float4* base = src4 + (long long)(c + 1) * SUMS_V4;
        for (int q = t - 64; q < SUMS_V4; q += SUMS_STG) {
          float4 v = base[q];
          if (which == 1) {
            v.x = fminf(v.x, 3.0f) + 0.001f;
            v.y = fminf(v.y, 3.0f) + 0.001f;
            v.z = fminf(v.z, 3.0f) + 0.001f;
            v.w = fminf(v.w, 3.0f) + 0.001f;
          }
          int k = q >> 1;
          int s0 = (q & 1) * 4;
          nxtb[(s0 + 0) * PSTRIPE + k] = v.x;
          nxtb[(s0 + 1) * PSTRIPE + k] = v.y;
          nxtb[(s0 + 2) * PSTRIPE + k] = v.z;
          nxtb[(s0 + 3) * PSTRIPE + k] = v.w;
        }
      }
    } else if (t < SUM_LANES) {
      const float4* stripe4 = (const float4*)(curb + t * PSTRIPE);
      float4 ld[SUMS_B4];
#pragma unroll
      for (int u = 0; u < SUMS_B4; ++u) ld[u] = stripe4[u];
      for (int b = 0; b < SUMS_NB; ++b) {
        float4 nx[SUMS_B4];
        if (b + 1 < SUMS_NB) {
          int boff = (b + 1) * SUMS_B4;
#pragma unroll
          for (int u = 0; u < SUMS_B4; ++u) nx[u] = stripe4[boff + u];
        }
#pragma unroll
        for (int u = 0; u < SUMS_B4; ++u) {
          acc += ld[u].x; acc += ld[u].y; acc += ld[u].z; acc += ld[u].w;
        }
        if (b + 1 < SUMS_NB) {
#pragma unroll
          for (int u = 0; u < SUMS_B4; ++u) ld[u] = nx[u];
        }
      }
    }
    __syncthreads();
  }

  if (t < SUM_LANES) lanes[t] = acc;
  __syncthreads();
  if (t == 0) {
    float v[SUM_LANES];
    for (int q = 0; q < SUM_LANES; ++q) v[q] = lanes[q];
    int w = SUM_LANES;
    while (w > 1) { int h = w >> 1; for (int q = 0; q < h; ++q) v[q] = v[q] + v[q + h]; w = h; }
    scf[which] = v[0];
  }
}

// keys: gum!=nullptr -> use precomputed Gumbel term (bit-identical order).
__global__ void keys_kernel(const float* warr, const float* att, const float* scf,
                            uint32_t* keys, uint2 kk, int mode, const float* gum) {
#pragma clang fp contract(off)
  int i = blockIdx.x * 256 + threadIdx.x;
  if (i >= E_EDGES) return;
  float S = (mode == 1) ? scf[SC_SSUB] : scf[SC_SKEEP];
  float w;
  if (mode == 1) { float a = att[i]; w = fminf(a, 3.0f) + 0.001f; }
  else w = warr[i];
  if (gum) {
    float p = w / S;
    float s = xla_logf(p) - gum[i];
    keys[i] = orderkey(s);
  } else {
    uint32_t b = rbits(kk, (uint32_t)i, 4000000u);
    keys[i] = score_key(w, S, unif_from_bits(b));
  }
}

__global__ void sel_reset_kernel(uint32_t* sc, uint32_t k) {
  int t = threadIdx.x;
  sc[SC_HIST + t] = 0u;
  if (t == 0) { sc[SC_PREFIX] = 0u; sc[SC_KPRIME] = k; sc[SC_EQC] = 0u; sc[SC_EQN] = 0u; }
}

__global__ void sel_hist_kernel(const uint32_t* keys, uint32_t* sc, int round) {
  __shared__ uint32_t h[256];
  int t = threadIdx.x;
  h[t] = 0u;
  __syncthreads();
  uint32_t pref = sc[SC_PREFIX];
  int shift = 24 - 8 * round;
  uint32_t maskHi = (round == 0) ? 0u : (0xFFFFFFFFu << (shift + 8));
  int i = blockIdx.x * 4096 + t;
#pragma unroll
  for (int it = 0; it < 16; ++it, i += 256) {
    if (i < E_EDGES) {
      uint32_t key = keys[i];
      if (((key ^ pref) & maskHi) == 0u) atomicAdd(&h[(key >> shift) & 0xffu], 1u);
    }
  }
  __syncthreads();
  if (h[t]) atomicAdd(&sc[SC_HIST + t], h[t]);
}

// parallel pick: 256 threads, reversed inclusive scan; same selection math.
__global__ void sel_pick_kernel(uint32_t* sc, int round) {
  __shared__ uint32_t s[256];
  int t = threadIdx.x;
  uint32_t kprime = sc[SC_KPRIME];
  uint32_t rh = sc[SC_HIST + 255 - t];   // thread t <-> bucket 255-t
  s[t] = rh;
  __syncthreads();
  for (int off = 1; off < 256; off <<= 1) {
    uint32_t x = 0; if (t >= off) x = s[t - off];
    __syncthreads();
    if (t >= off) s[t] += x;
    __syncthreads();
  }
  // scanned[t] = suffix-inclusive sum for bucket 255-t (nondecreasing in t).
  uint32_t inc = s[t];
  uint32_t prev = (t == 0) ? 0u : s[t - 1];
  int win = (inc >= kprime) && (prev < kprime);
  __syncthreads();
  sc[SC_HIST + t] = 0u;   // parallel hist clear for next round
  if (win) {
    uint32_t bsel = (uint32_t)(255 - t);
    int shift = 24 - 8 * round;
    uint32_t newpref = sc[SC_PREFIX] | (bsel << shift);
    sc[SC_PREFIX] = newpref;
    uint32_t nk = kprime - prev;
    sc[SC_KPRIME] = nk;
    if (round == 3) { sc[SC_T] = newpref; sc[SC_M] = nk; }
  }
}

__global__ void eq_collect_kernel(const uint32_t* keys, uint32_t* sc, uint32_t* eql) {
  int i = blockIdx.x * 256 + threadIdx.x;
  if (i >= E_EDGES) return;
  if (keys[i] == sc[SC_T]) {
    uint32_t p = atomicAdd(&sc[SC_EQC], 1u);
    if (p < 4096u) eql[p] = (uint32_t)i;
  }
}

__global__ void eq_sort_kernel(uint32_t* sc, uint32_t* eql) {
  if (blockIdx.x != 0 || threadIdx.x != 0) return;
  uint32_t n = sc[SC_EQC]; if (n > 4096u) n = 4096u;
  sc[SC_EQN] = n;
  for (uint32_t a = 1; a < n; ++a) {
    uint32_t v = eql[a]; uint32_t b = a;
    while (b > 0 && eql[b - 1] > v) { eql[b] = eql[b - 1]; --b; }
    eql[b] = v;
  }
}

__device__ __forceinline__ int keep_flag(uint32_t key, uint32_t T, uint32_t m,
                                         const uint32_t* eql, uint32_t eqn, uint32_t i) {
  if (key > T) return 1;
  if (key != T) return 0;
  uint32_t lo = 0, hi = eqn;
  while (lo < hi) { uint32_t mid = (lo + hi) >> 1; if (eql[mid] < i) lo = mid + 1; else hi = mid; }
  return (lo < m) ? 1 : 0;
}

__global__ void cnt_flags_kernel(const uint32_t* keys, const uint32_t* sc,
                                 const uint32_t* eql, uint32_t* sblk) {
  __shared__ uint32_t s[256];
  int t = threadIdx.x;
  uint32_t T = sc[SC_T], m = sc[SC_M], eqn = sc[SC_EQN];
  int base = blockIdx.x * 4096 + t * 16;
  uint32_t cnt = 0;
#pragma unroll
  for (int j = 0; j < 16; ++j) {
    int i = base + j;
    if (i < E_EDGES) cnt += keep_flag(keys[i], T, m, eql, eqn, (uint32_t)i);
  }
  s[t] = cnt;
  __syncthreads();
  for (int off = 128; off > 0; off >>= 1) { if (t < off) s[t] += s[t + off]; __syncthreads(); }
  if (t == 0) sblk[blockIdx.x] = s[0];
}

__global__ void scan_small_kernel(uint32_t* a, int n, uint32_t* totalOut) {
  __shared__ uint32_t s[256];
  int t = threadIdx.x;
  uint32_t carry = 0;
  for (int base = 0; base < n; base += 256) {
    int idx = base + t;
    uint32_t v = (idx < n) ? a[idx] : 0u;
    s[t] = v;
    __syncthreads();
    for (int off = 1; off < 256; off <<= 1) {
      uint32_t x = 0; if (t >= off) x = s[t - off];
      __syncthreads();
      if (t >= off) s[t] += x;
      __syncthreads();
    }
    uint32_t incl = s[t];
    uint32_t tot = s[255];
    if (idx < n) a[idx] = incl - v + carry;
    carry += tot;
    __syncthreads();
  }
  if (t == 0 && totalOut) *totalOut = carry;
}

__global__ void hscan1_kernel(uint32_t* a, int n, uint32_t* part) {
  __shared__ uint32_t s[256];
  int t = threadIdx.x;
  int idx = blockIdx.x * 256 + t;
  uint32_t v = (idx < n) ? a[idx] : 0u;
  s[t] = v;
  __syncthreads();
  for (int off = 1; off < 256; off <<= 1) {
    uint32_t x = 0; if (t >= off) x = s[t - off];
    __syncthreads();
    if (t >= off) s[t] += x;
    __syncthreads();
  }
  if (idx < n) a[idx] = s[t] - v;
  if (t == 255) part[blockIdx.x] = s[255];
}

__global__ void hscan3_kernel(uint32_t* a, int n, const uint32_t* part) {
  int idx = blockIdx.x * 256 + threadIdx.x;
  if (idx < n) a[idx] += part[blockIdx.x];
}

__global__ void scatter_kernel(const uint32_t* keys, const uint32_t* sc, const uint32_t* eql,
                               const uint32_t* sblk, int* kidx, int* didx, int writeDrop) {
  __shared__ uint32_t s[256];
  int t = threadIdx.x;
  uint32_t T = sc[SC_T], m = sc[SC_M], eqn = sc[SC_EQN];
  int base = blockIdx.x * 4096 + t * 16;
  uint32_t fbits = 0, cnt = 0;
#pragma unroll
  for (int j = 0; j < 16; ++j) {
    int i = base + j; int f = 0;
    if (i < E_EDGES) f = keep_flag(keys[i], T, m, eql, eqn, (uint32_t)i);
    fbits |= ((uint32_t)f) << j; cnt += (uint32_t)f;
  }
  s[t] = cnt;
  __syncthreads();
  for (int off = 1; off < 256; off <<= 1) {
    uint32_t x = 0; if (t >= off) x = s[t - off];
    __syncthreads();
    if (t >= off) s[t] += x;
    __syncthreads();
  }
  uint32_t run = sblk[blockIdx.x] + (s[t] - cnt);
  for (int j = 0; j < 16; ++j) {
    int i = base + j;
    if (i >= E_EDGES) break;
    if ((fbits >> j) & 1u) {
      if (run < 4000000u) kidx[run] = i;
      run++;
    } else if (writeDrop) {
      uint32_t d = (uint32_t)i - run;
      if (d < 4000000u) didx[d] = i;
    }
  }
}

__global__ void build_rows_kernel(const int* kidx, const int* ar, const int* ac,
                                  int* rows, int* cols, int total) {
  int i = blockIdx.x * 256 + threadIdx.x;
  if (i >= total) return;
  if (i < NVERT) { rows[i] = i; cols[i] = i; }
  else {
    int j = kidx[i - NVERT];
    j = (j < 0) ? 0 : (j >= E_EDGES ? E_EDGES - 1 : j);
    rows[i] = ar[j]; cols[i] = ac[j];
  }
}

__global__ void deg_count_kernel(const int* rows, int* deg, int len) {
  int i = blockIdx.x * 256 + threadIdx.x;
  if (i >= len) return;
  int r = rows[i];
  r = (r < 0) ? 0 : (r >= NVERT ? NVERT - 1 : r);
  atomicAdd(&deg[r], 1);
}

__global__ void deg_inv_kernel(const int* deg, float* dinv) {
  int i = blockIdx.x * 256 + threadIdx.x;
  if (i >= NVERT) return;
  int d = deg[i];
  dinv[i] = (d > 0) ? (float)(1.0 / sqrt((double)d)) : 0.0f;
}

__global__ void graph_out_kernel(const int* rows, const int* cols, const float* dinv,
                                 float* outb, long long idxOff, long long valOff, int len) {
#pragma clang fp contract(off)
  int i = blockIdx.x * 256 + threadIdx.x;
  if (i >= len) return;
  int r = rows[i], c = cols[i];
  r = (r < 0) ? 0 : (r >= NVERT ? NVERT - 1 : r);
  c = (c < 0) ? 0 : (c >= NVERT ? NVERT - 1 : c);
  outb[idxOff + i] = (float)r;
  outb[idxOff + len + i] = (float)c;
  outb[valOff + i] = dinv[r] * dinv[c];
}

__global__ void newrc_kernel(const int* rows, const int* cols, const int* didx,
                             const int* ar, const int* ac, int* newr, int* newc,
                             uint2 knr1, uint2 knr2, uint2 knc1, uint2 knc2,
                             uint2 ker1, uint2 ker2, uint2 kec1, uint2 kec2) {
  int i = blockIdx.x * 256 + threadIdx.x;
  if (i >= N_NEW) return;
  uint32_t nr = jrandint(knr1, knr2, (uint32_t)i, 3200000u, SPAN_NEW);
  int v;
  if (nr < (uint32_t)N_EXT) {
    uint32_t e = jrandint(ker1, ker2, nr, 1000000u, SPAN_EXT);
    v = rows[e];
  } else {
    int d = didx[nr - (uint32_t)N_EXT];
    d = (d < 0) ? 0 : (d >= E_EDGES ? E_EDGES - 1 : d);
    v = ar[d];
  }
  newr[i] = v;
  uint32_t nc = jrandint(knc1, knc2, (uint32_t)i, 3200000u, SPAN_NEW);
  if (nc < (uint32_t)N_EXT) {
    uint32_t e = jrandint(kec1, kec2, nc, 1000000u, SPAN_EXT);
    v = cols[e];
  } else {
    int d = didx[nc - (uint32_t)N_EXT];
    d = (d < 0) ? 0 : (d >= E_EDGES ? E_EDGES - 1 : d);
    v = ac[d];
  }
  newc[i] = v;
}

__global__ void bmp_mark_kernel(const int* newr, const int* newc,
                                const int* rows, const int* cols, uint32_t* bmp) {
  int i = blockIdx.x * 256 + threadIdx.x;
  if (i >= DEC_LEN) return;
  int r, c;
  if (i < N_NEW) { r = newr[i]; c = newc[i]; }
  else if (i < 2 * N_NEW) { r = newc[i - N_NEW]; c = newr[i - N_NEW]; }
  else if (i < 2 * N_NEW + NVERT) { r = i - 2 * N_NEW; c = r; }
  else { int q = i - (2 * N_NEW + NVERT); r = rows[q]; c = cols[q]; }
  r = (r < 0) ? 0 : (r >= NVERT ? NVERT - 1 : r);
  c = (c < 0) ? 0 : (c >= NVERT ? NVERT - 1 : c);
  uint32_t h = (uint32_t)r * 44000u + (uint32_t)c;
  atomicOr(&bmp[h >> 5], 1u << (h & 31u));
}

__global__ void bmp_cnt_kernel(const uint32_t* bmp, uint32_t* blk) {
  __shared__ uint32_t s[256];
  int t = threadIdx.x;
  long long wbase = (long long)blockIdx.x * 1024 + (long long)t * 4;
  uint32_t c = 0;
#pragma unroll
  for (int j = 0; j < 4; ++j) {
    long long w = wbase + j;
    if (w < (long long)BMP_WORDS) c += __popc(bmp[w]);
  }
  s[t] = c;
  __syncthreads();
  for (int off = 128; off > 0; off >>= 1) { if (t < off) s[t] += s[t + off]; __syncthreads(); }
  if (t == 0) blk[blockIdx.x] = s[0];
}

__global__ void dec_out_kernel(const uint32_t* bmp, const uint32_t* blk, float* outb) {
  __shared__ uint32_t s[256];
  int t = threadIdx.x;
  long long wbase = (long long)blockIdx.x * 1024 + (long long)t * 4;
  uint32_t cn[4]; uint32_t tot = 0;
#pragma unroll
  for (int j = 0; j < 4; ++j) {
    long long w = wbase + j;
    cn[j] = (w < (long long)BMP_WORDS) ? (uint32_t)__popc(bmp[w]) : 0u;
    tot += cn[j];
  }
  s[t] = tot;
  __syncthreads();
  for (int off = 1; off < 256; off <<= 1) {
    uint32_t x = 0; if (t >= off) x = s[t - off];
    __syncthreads();
    if (t >= off) s[t] += x;
    __syncthreads();
  }
  uint32_t pos = blk[blockIdx.x] + (s[t] - tot);
  for (int j = 0; j < 4; ++j) {
    long long w = wbase + j;
    if (w >= (long long)BMP_WORDS) break;
    uint32_t word = bmp[w];
    while (word) {
      int b = __ffs(word) - 1;
      word &= word - 1u;
      uint32_t v = (uint32_t)w * 32u + (uint32_t)b;
      uint32_t ur = v / 44000u;
      uint32_t uc = v - ur * 44000u;
      if (pos < (uint32_t)DEC_LEN) {
        outb[O2 + pos] = (float)ur;
        outb[O2 + DEC_LEN + pos] = (float)uc;
        outb[O3 + pos] = 1.0f;
      }
      pos++;
    }
  }
}

__global__ void dec_pad_kernel(float* outb, const uint32_t* sc) {
  int p = blockIdx.x * 256 + threadIdx.x;
  if (p >= DEC_LEN) return;
  if ((uint32_t)p >= sc[SC_MUNIQ]) {
    outb[O2 + p] = 0.0f; outb[O2 + DEC_LEN + p] = 0.0f; outb[O3 + p] = 0.0f;
  }
}

// ---------------------------------------------------------------------------
static void jsplit2(uint2 k, uint2& k1, uint2& k2) {
#if PARTITIONABLE
  TF2 a = tf2x32(k.x, k.y, 0u, 0u), b = tf2x32(k.x, k.y, 0u, 1u);
  k1.x = a.a; k1.y = a.b; k2.x = b.a; k2.y = b.b;
#else
  TF2 a = tf2x32(k.x, k.y, 0u, 2u), b = tf2x32(k.x, k.y, 1u, 3u);
  k1.x = a.a; k1.y = b.a; k2.x = a.b; k2.y = b.b;
#endif
}

extern "C" void kernel_launch(void* const* d_in, const int* in_sizes, int n_in,
                              void* d_out, int out_size, void* d_ws, size_t ws_size,
                              hipStream_t stream) {
  float* outb = (float*)d_out;

  if (out_size != OUT_TOTAL) {
    sentinel_kernel<<<1, 64, 0, stream>>>(outb, 16777216.0f);
    return;
  }
  if (n_in < 4 || in_sizes[0] != E_EDGES || in_sizes[3] != E_EDGES) {
    sentinel_kernel<<<1, 64, 0, stream>>>(outb, 20971520.0f);
    return;
  }
  if (ws_size < 429300000ULL) {
    sentinel_kernel<<<1, 64, 0, stream>>>(outb, 25165824.0f);
    return;
  }

  const int* adj_rows = (const int*)d_in[0];
  const int* adj_cols = (const int*)d_in[1];
  const float* att = (const float*)d_in[3];
  char* ws = (char*)d_ws;

  uint32_t* KEYS  = (uint32_t*)(ws + 0LL);
  float*    WARR  = (float*)(ws + 32000000LL);
  int*      KIDX  = (int*)(ws + 64000000LL);
  int*      DIDX  = (int*)(ws + 80000000LL);
  int*      ROWS  = (int*)(ws + 96000000LL);
  int*      COLS  = (int*)(ws + 112176000LL);
  int*      NEWR  = (int*)(ws + 128352000LL);
  int*      NEWC  = (int*)(ws + 153952000LL);
  uint32_t* BMP   = (uint32_t*)(ws + 179552000LL);
  uint32_t* BLK   = (uint32_t*)(ws + 421552000LL);
  int*      DEG   = (int*)(ws + 421788544LL);
  float*    DINV  = (float*)(ws + 421964544LL);
  uint32_t* SBLK  = (uint32_t*)(ws + 422140544LL);
  uint32_t* SC    = (uint32_t*)(ws + 422148736LL);
  uint32_t* EQL   = (uint32_t*)(ws + 422152832LL);
  int*      CMPR  = (int*)(ws + 422169216LL);
  int*      CMPC  = (int*)(ws + 425545216LL);
  float*    DINVS = (float*)(ws + 428921216LL);
  float*    DINVC = (float*)(ws + 429097216LL);
  uint32_t* PART  = SC + SC_PART;

  const int useG = (ws_size >= WS_NEED_G) ? 1 : 0;
  float* GUM = useG ? (float*)(ws + GUM_OFF) : nullptr;
  float* GUM_K = GUM;
  float* GUM_S = useG ? GUM + 8000000 : nullptr;
  float* GUM_C = useG ? GUM + 16000000 : nullptr;

  TF2 K[7];
#if PARTITIONABLE
  for (int i = 0; i < 7; ++i) K[i] = tf2x32(0u, 42u, 0u, (uint32_t)i);
#else
  {
    TF2 T_[7];
    for (int i = 0; i < 7; ++i) T_[i] = tf2x32(0u, 42u, (uint32_t)i, (uint32_t)(7 + i));
    K[0].a = T_[0].a; K[0].b = T_[1].a;
    K[1].a = T_[2].a; K[1].b = T_[3].a;
    K[2].a = T_[4].a; K[2].b = T_[5].a;
    K[3].a = T_[6].a; K[3].b = T_[0].b;
    K[4].a = T_[1].b; K[4].b = T_[2].b;
    K[5].a = T_[3].b; K[5].b = T_[4].b;
    K[6].a = T_[5].b; K[6].b = T_[6].b;
  }
#endif
  uint2 kkeep, ker, kec, knr, knc, ksub, kcmp;
  kkeep.x = K[0].a; kkeep.y = K[0].b;
  ker.x = K[1].a; ker.y = K[1].b;
  kec.x = K[2].a; kec.y = K[2].b;
  knr.x = K[3].a; knr.y = K[3].b;
  knc.x = K[4].a; knc.y = K[4].b;
  ksub.x = K[5].a; ksub.y = K[5].b;
  kcmp.x = K[6].a; kcmp.y = K[6].b;
  uint2 ker1, ker2, kec1, kec2, knr1, knr2, knc1, knc2;
  jsplit2(ker, ker1, ker2); jsplit2(kec, kec1, kec2);
  jsplit2(knr, knr1, knr2); jsplit2(knc, knc1, knc2);

  // === Phase A: SC zero + w + mega dispatch (sums | zeros | gumbel) ===
  zero_kernel<<<1, 256, 0, stream>>>(SC, 1024LL);
  w_kernel<<<31250, 256, 0, stream>>>(att, WARR);
  int megaBlocks = MB_SUMS + MB_ZBMP + MB_ZKD + (useG ? MB_G : 0);
  phaseA_kernel<<<megaBlocks, 512, 0, stream>>>(WARR, att, (float*)SC, BMP,
                                                (uint32_t*)KIDX, GUM,
                                                kkeep, ksub, kcmp);

  auto run_select = [&](uint32_t kcount) {
    sel_reset_kernel<<<1, 256, 0, stream>>>(SC, kcount);
    for (int r = 0; r < 4; ++r) {
      sel_hist_kernel<<<NBLK_E, 256, 0, stream>>>(KEYS, SC, r);
      sel_pick_kernel<<<1, 256, 0, stream>>>(SC, r);
    }
    eq_collect_kernel<<<31250, 256, 0, stream>>>(KEYS, SC, EQL);
    eq_sort_kernel<<<1, 64, 0, stream>>>(SC, EQL);
    cnt_flags_kernel<<<NBLK_E, 256, 0, stream>>>(KEYS, SC, EQL, SBLK);
    hscan1_kernel<<<NBLK_B, 256, 0, stream>>>(SBLK, NBLK_E, PART);
    scan_small_kernel<<<1, 256, 0, stream>>>(PART, NBLK_B, (uint32_t*)nullptr);
    hscan3_kernel<<<NBLK_B, 256, 0, stream>>>(SBLK, NBLK_E, PART);
  };

  // === Phase B: encoder keep selection (k=4M) -> ROWS/COLS/DINV ===
  keys_kernel<<<31250, 256, 0, stream>>>(WARR, att, (const float*)SC, KEYS, kkeep, 0, GUM_K);
  run_select(4000000u);
  scatter_kernel<<<NBLK_E, 256, 0, stream>>>(KEYS, SC, EQL, SBLK, KIDX, DIDX, 1);
  build_rows_kernel<<<15797, 256, 0, stream>>>(KIDX, adj_rows, adj_cols, ROWS, COLS, ROWS_LEN);
  zero_kernel<<<172, 256, 0, stream>>>((uint32_t*)DEG, (long long)NVERT);
  deg_count_kernel<<<15797, 256, 0, stream>>>(ROWS, DEG, ROWS_LEN);
  deg_inv_kernel<<<172, 256, 0, stream>>>(DEG, DINV);

  // === Phase C: decoder rewire + bitmap unique -> BMP/BLK/MUNIQ ===
  newrc_kernel<<<25000, 256, 0, stream>>>(ROWS, COLS, DIDX, adj_rows, adj_cols, NEWR, NEWC,
                                          knr1, knr2, knc1, knc2, ker1, ker2, kec1, kec2);
  bmp_mark_kernel<<<65969, 256, 0, stream>>>(NEWR, NEWC, ROWS, COLS, BMP);
  bmp_cnt_kernel<<<NSCB, 256, 0, stream>>>(BMP, BLK);
  hscan1_kernel<<<NSCB_B, 256, 0, stream>>>(BLK, NSCB, PART);
  scan_small_kernel<<<1, 256, 0, stream>>>(PART, NSCB_B, &SC[SC_MUNIQ]);
  hscan3_kernel<<<NSCB_B, 256, 0, stream>>>(BLK, NSCB, PART);

  // === Phase D: sub selection (k=800k) ===
  keys_kernel<<<31250, 256, 0, stream>>>(WARR, att, (const float*)SC, KEYS, ksub, 1, GUM_S);
  run_select(800000u);
  scatter_kernel<<<NBLK_E, 256, 0, stream>>>(KEYS, SC, EQL, SBLK, KIDX, (int*)nullptr, 0);
  build_rows_kernel<<<3297, 256, 0, stream>>>(KIDX, adj_rows, adj_cols, NEWR, NEWC, SROWS_LEN);
  zero_kernel<<<172, 256, 0, stream>>>((uint32_t*)DEG, (long long)NVERT);
  deg_count_kernel<<<3297, 256, 0, stream>>>(NEWR, DEG, SROWS_LEN);
  deg_inv_kernel<<<172, 256, 0, stream>>>(DEG, DINVS);

  // === Phase E: cmp selection (k=800k) ===
  keys_kernel<<<31250, 256, 0, stream>>>(WARR, att, (const float*)SC, KEYS, kcmp, 2, GUM_C);
  run_select(800000u);
  scatter_kernel<<<NBLK_E, 256, 0, stream>>>(KEYS, SC, EQL, SBLK, KIDX, (int*)nullptr, 0);
  build_rows_kernel<<<3297, 256, 0, stream>>>(KIDX, adj_rows, adj_cols, CMPR, CMPC, SROWS_LEN);
  zero_kernel<<<172, 256, 0, stream>>>((uint32_t*)DEG, (long long)NVERT);
  deg_count_kernel<<<3297, 256, 0, stream>>>(CMPR, DEG, SROWS_LEN);
  deg_inv_kernel<<<172, 256, 0, stream>>>(DEG, DINVC);

  // === Phase F: EMIT ALL OUTPUTS (f32, natural return order) ===
  dec_out_kernel<<<NSCB, 256, 0, stream>>>(BMP, BLK, outb);
  dec_pad_kernel<<<65969, 256, 0, stream>>>(outb, SC);
  graph_out_kernel<<<3297, 256, 0, stream>>>(NEWR, NEWC, DINVS, outb, O4, O5, SROWS_LEN);
  graph_out_kernel<<<3297, 256, 0, stream>>>(CMPR, CMPC, DINVC, outb, O6, O7, SROWS_LEN);
  graph_out_kernel<<<15797, 256, 0, stream>>>(ROWS, COLS, DINV, outb, O0, O1, ROWS_LEN);
}